// Round 19
// baseline (726.824 us; speedup 1.0000x reference)
//
#include <hip/hip_runtime.h>
#include <hip/hip_bf16.h>
#include <cstdint>
#include <cstddef>

#define T_TOK 8192
#define H_DIM 2048
#define I_DIM 1408
#define E_NUM 8
#define BM 128
#define BK 64
#define ROWS_CAP (2 * T_TOK + E_NUM * BM) /* 17408 */
#define MAX_MT (ROWS_CAP / BM)            /* 136 */
#define NT1 (I_DIM / 64)                  /* 22 */
#define NT2 (H_DIM / 128)                 /* 16 */
#define NTILE_GU (44 * 16 * E_NUM)        /* 5632 */
#define NTILE_DN (32 * 11 * E_NUM)        /* 2816 */
#define NTILE_TOT (NTILE_GU + NTILE_DN)   /* 8448 */
#define TCVT_NB 2048

typedef __attribute__((ext_vector_type(8))) short short8;
typedef __attribute__((ext_vector_type(4))) float f32x4;
typedef __attribute__((ext_vector_type(8))) unsigned short bf16x8;
typedef __attribute__((ext_vector_type(4))) unsigned short bf16x4;
typedef __attribute__((ext_vector_type(8))) _Float16 h16x8;

static __device__ __forceinline__ unsigned short f2bf(float f) {
  unsigned u = __float_as_uint(f);
  u += 0x7FFFu + ((u >> 16) & 1u);   // round-to-nearest-even
  return (unsigned short)(u >> 16);
}

static __device__ __forceinline__ void gld_lds16(const void* g, void* l) {
  __builtin_amdgcn_global_load_lds(
      (__attribute__((address_space(1))) unsigned int*)g,
      (__attribute__((address_space(3))) unsigned int*)l, 16, 0, 0);
}

// XCD-chunked bijective remap (nb % 8 == 0) + M-groups-of-G intra order.
template <int G>
static __device__ __forceinline__ void remap_tile(int bid, int nb, int nt_cols,
                                                  int& m_t, int& n_t) {
  int chunk = nb >> 3;
  int wg = (bid & 7) * chunk + (bid >> 3);
  int grp = wg / (nt_cols * G);
  int rem = wg % (nt_cols * G);
  n_t = rem / G;
  m_t = grp * G + rem % G;
}

// ---------------- router (fused x->bf16 convert) ---------------------------
__global__ __launch_bounds__(256) void router_kernel(
    const float* __restrict__ x, const float* __restrict__ rw,
    unsigned short* __restrict__ xb,
    int* __restrict__ topk_idx, float* __restrict__ topk_w, int* __restrict__ meta) {
  int t = blockIdx.x * 4 + (threadIdx.x >> 6);
  int lane = threadIdx.x & 63;
  const float* xr = x + (size_t)t * H_DIM;
  unsigned short* xbr = xb + (size_t)t * H_DIM;
  float acc[E_NUM];
#pragma unroll
  for (int e = 0; e < E_NUM; e++) acc[e] = 0.f;
  for (int j = lane * 4; j < H_DIM; j += 256) {
    f32x4 v = *(const f32x4*)(xr + j);
    bf16x4 b;
#pragma unroll
    for (int u = 0; u < 4; u++) b[u] = f2bf(v[u]);
    *(bf16x4*)(xbr + j) = b;
#pragma unroll
    for (int e = 0; e < E_NUM; e++) {
      f32x4 w = *(const f32x4*)(rw + e * H_DIM + j);
      acc[e] += v[0] * w[0] + v[1] * w[1] + v[2] * w[2] + v[3] * w[3];
    }
  }
#pragma unroll
  for (int e = 0; e < E_NUM; e++) {
    float v = acc[e];
#pragma unroll
    for (int s = 32; s > 0; s >>= 1) v += __shfl_xor(v, s);
    acc[e] = v;
  }
  if (lane == 0) {
    int i0 = 0;
#pragma unroll
    for (int e = 1; e < E_NUM; e++) if (acc[e] > acc[i0]) i0 = e;
    int i1 = (i0 == 0) ? 1 : 0;
#pragma unroll
    for (int e = 0; e < E_NUM; e++) if (e != i0 && acc[e] > acc[i1]) i1 = e;
    float mx = acc[0];
#pragma unroll
    for (int e = 1; e < E_NUM; e++) mx = fmaxf(mx, acc[e]);
    float sum = 0.f, p[E_NUM];
#pragma unroll
    for (int e = 0; e < E_NUM; e++) { p[e] = expf(acc[e] - mx); sum += p[e]; }
    float inv = 1.f / sum;
    topk_idx[t * 2] = i0;  topk_idx[t * 2 + 1] = i1;
    topk_w[t * 2] = p[i0] * inv;  topk_w[t * 2 + 1] = p[i1] * inv;
    atomicAdd(&meta[i0], 1);
    atomicAdd(&meta[i1], 1);
  }
}

// ---------------- scan -----------------------------------------------------
__global__ void scan_kernel(int* __restrict__ meta, int* __restrict__ row_token) {
  __shared__ int s_off[E_NUM + 1];
  if (threadIdx.x == 0) {
    int o = 0, nt = 0;
    for (int e = 0; e < E_NUM; e++) {
      meta[16 + e] = o; s_off[e] = o;
      int c = meta[e];
      int mtc = (c + BM - 1) / BM;
      for (int m = 0; m < mtc; m++) { meta[64 + nt] = e; meta[256 + nt] = o + m * BM; nt++; }
      o += mtc * BM;
      meta[8 + e] = 0; // cursor
    }
    meta[16 + E_NUM] = o; s_off[E_NUM] = o;
    meta[32] = nt;
  }
  __syncthreads();
  for (int e = 0; e < E_NUM; e++) {
    int lo = s_off[e] + meta[e], hi = s_off[e + 1];
    for (int r = lo + (int)threadIdx.x; r < hi; r += 64) row_token[r] = -1;
  }
}

// ---------------- bucket ---------------------------------------------------
__global__ __launch_bounds__(256) void bucket_kernel(
    const int* __restrict__ topk_idx, int* __restrict__ meta,
    int* __restrict__ row_token, int* __restrict__ tok2row) {
  int i = blockIdx.x * 256 + threadIdx.x;
  if (i >= 2 * T_TOK) return;
  int e = topk_idx[i];
  int pos = atomicAdd(&meta[8 + e], 1);
  int r = meta[16 + e] + pos;
  row_token[r] = i >> 1;
  tok2row[i] = r;
}

// ---------------- transpose+convert: pipelined gld_lds (counted vmcnt) -----
// Tiles of 128 k-rows x 64 n-cols fp32 (32 KB), double-buffered; grid-stride.
// stage(next) -> vmcnt(8) [cur ready] -> barrier -> transposed b128 writes
// -> barrier -> flip. Source pre-swizzled (key(r)=(r&7)^((r>>3)&7)), LDS
// dest linear (m104); reads 2-way bank (free); 256B read+write runs.
__global__ __launch_bounds__(256) void tcvt2_kernel(
    const float* __restrict__ wgu, const float* __restrict__ wdn,
    unsigned short* __restrict__ wgu_t, unsigned short* __restrict__ wd_t) {
  __shared__ alignas(16) float st[2][128 * 64];  // 2 x 32 KB
  int tid = threadIdx.x, l = tid & 63, w = tid >> 6;

  auto decode = [&](int t, const float*& src, unsigned short*& dst,
                    int& R, int& C, int& c0, int& r0) {
    if (t < NTILE_GU) {
      int e = t / 704, rem = t % 704;
      R = H_DIM; C = 2 * I_DIM;
      c0 = (rem % 44) * 64; r0 = (rem / 44) * 128;
      src = wgu + (size_t)e * R * C;
      dst = wgu_t + (size_t)e * R * C;
    } else {
      int tt = t - NTILE_GU;
      int e = tt / 352, rem = tt % 352;
      R = I_DIM; C = H_DIM;
      c0 = (rem % 32) * 64; r0 = (rem / 32) * 128;
      src = wdn + (size_t)e * R * C;
      dst = wd_t + (size_t)e * R * C;
    }
  };

  auto stage = [&](int buf, int t) {
    const float* src; unsigned short* dst; int R, C, c0, r0;
    decode(t, src, dst, R, C, c0, r0);
#pragma unroll
    for (int i = 0; i < 8; i++) {
      int rbase = w * 32 + i * 4;
      int r = rbase + (l >> 4);
      int key = (r & 7) ^ ((r >> 3) & 7);
      int c4 = ((l & 15) ^ key) * 4;  // pre-swizzled source col (f32)
      gld_lds16(src + (size_t)(r0 + r) * C + c0 + c4,
                (char*)&st[buf][0] + rbase * 256);
    }
  };

  auto process = [&](int buf, int t) {
    const float* src; unsigned short* dst; int R, C, c0, r0;
    decode(t, src, dst, R, C, c0, r0);
    int ca = tid & 15, cg = tid >> 4;
#pragma unroll
    for (int it = 0; it < 4; it++) {
      int c = it * 16 + cg;
      bf16x8 o;
#pragma unroll
      for (int j = 0; j < 8; j++) {
        int r = ca * 8 + j;
        int key = (r & 7) ^ ((r >> 3) & 7);
        o[j] = f2bf(st[buf][r * 64 + (((c >> 2) ^ key) << 2) + (c & 3)]);
      }
      *(bf16x8*)(dst + (size_t)(c0 + c) * R + r0 + ca * 8) = o;
    }
  };

  int t = blockIdx.x;
  if (t >= NTILE_TOT) return;
  int nxt = t + TCVT_NB;
  stage(0, t);
  int buf = 0;
  while (true) {
    bool has_next = (nxt < NTILE_TOT);
    if (has_next) {
      stage(buf ^ 1, nxt);
      asm volatile("s_waitcnt vmcnt(8)" ::: "memory");  // cur's 8 loads done
    } else {
      asm volatile("s_waitcnt vmcnt(0)" ::: "memory");
    }
    __builtin_amdgcn_s_barrier();
    process(buf, t);
    if (!has_next) break;
    asm volatile("" ::: "memory");
    __builtin_amdgcn_s_barrier();   // WAR: all waves done reading buf
    t = nxt; nxt += TCVT_NB; buf ^= 1;
  }
}

// ---------------- GEMM1: h = silu(x@Wg)*(x@Wu) -----------------------------
// Counted-vmcnt pipeline (T4): 2 buffers, prefetch distance 2, raw barriers,
// never drain vmcnt to 0 in steady state.
__global__ __launch_bounds__(256) void gemm1_kernel(
    const unsigned short* __restrict__ xb,   // [T][H] bf16
    const unsigned short* __restrict__ wgu,  // [E][2I][H] bf16 (transposed)
    unsigned short* __restrict__ hbuf,       // [ROWS_CAP][I] bf16
    const int* __restrict__ row_token, const int* __restrict__ meta) {
  int m_t, n_t;
  remap_tile<4>(blockIdx.x, NT1 * MAX_MT, NT1, m_t, n_t);
  if (m_t >= meta[32]) return;
  int e = meta[64 + m_t];
  int row0 = meta[256 + m_t];
  int n0h = n_t * 64;

  __shared__ alignas(16) char smem[65536];  // 2 x (A 16K + B 16K)

  int tid = threadIdx.x, lane = tid & 63, wid = tid >> 6;
  const unsigned short* asrc[4];
  const unsigned short* bsrc[4];
  {
    const unsigned short* wb = wgu + (size_t)e * (2 * (size_t)I_DIM) * H_DIM;
#pragma unroll
    for (int i = 0; i < 4; i++) {
      int r = i * 32 + (tid >> 3);
      int ch = ((tid & 7) ^ (r & 7)) * 8;  // inverse-swizzled source chunk
      int tok = row_token[row0 + r];
      if (tok < 0) tok = 0;
      asrc[i] = xb + (size_t)tok * H_DIM + ch;
      int wr = (r < 64) ? (n0h + r) : (I_DIM + n0h + (r - 64));
      bsrc[i] = wb + (size_t)wr * H_DIM + ch;
    }
  }
  f32x4 acc[4][4] = {};
  int mrow = (wid >> 1) * 64 + (lane & 15);
  int brow = (wid & 1) * 64 + (lane & 15);

#define STAGE1(buf, kof_)                                                     \
  {                                                                           \
    int kof = (kof_);                                                         \
    char* b = smem + (buf) * 32768;                                           \
    _Pragma("unroll") for (int i = 0; i < 4; i++) {                           \
      gld_lds16(asrc[i] + kof, b + i * 4096 + wid * 1024);                    \
      gld_lds16(bsrc[i] + kof, b + 16384 + i * 4096 + wid * 1024);            \
    }                                                                         \
  }

  constexpr int NK1 = H_DIM / BK;  // 32
  STAGE1(0, 0);
  STAGE1(1, BK);
  for (int kt = 0; kt < NK1; kt++) {
    int cur = kt & 1;
    // wait my 8 loads for cur (leave the next tile's 8 in flight)
    if (kt + 1 < NK1) { asm volatile("s_waitcnt vmcnt(8)" ::: "memory"); }
    else              { asm volatile("s_waitcnt vmcnt(0)" ::: "memory"); }
    __builtin_amdgcn_s_barrier();   // all waves' loads for cur are in LDS
    const unsigned short* sA = (const unsigned short*)(smem + cur * 32768);
    const unsigned short* sB = sA + 8192;
#pragma unroll
    for (int kk = 0; kk < 2; kk++) {
      int krd = ((kk * 4 + (lane >> 4)) ^ (lane & 7)) * 8;
      short8 af[4], bf[4];
#pragma unroll
      for (int f = 0; f < 4; f++) {
        af[f] = *(const short8*)(sA + (mrow + f * 16) * BK + krd);
        bf[f] = *(const short8*)(sB + (brow + f * 16) * BK + krd);
      }
#pragma unroll
      for (int fm = 0; fm < 4; fm++)
#pragma unroll
        for (int fn = 0; fn < 4; fn++)
          acc[fm][fn] = __builtin_amdgcn_mfma_f32_16x16x32_bf16(af[fm], bf[fn], acc[fm][fn], 0, 0, 0);
    }
    asm volatile("" ::: "memory");
    __builtin_amdgcn_s_barrier();   // all waves done reading cur (WAR fence)
    asm volatile("" ::: "memory");
    if (kt + 2 < NK1) STAGE1(cur, (kt + 2) * BK);
  }

  // SwiGLU epilogue (known-good): odd waves publish U via LDS, even combine.
  float* xw = (float*)smem + (wid >> 1) * 4096;  // 64x64 f32 per wave-pair
  if (wid & 1) {
#pragma unroll
    for (int fm = 0; fm < 4; fm++)
#pragma unroll
      for (int r = 0; r < 4; r++) {
        int mloc = fm * 16 + (lane >> 4) * 4 + r;
#pragma unroll
        for (int fn = 0; fn < 4; fn++)
          xw[mloc * 64 + fn * 16 + (lane & 15)] = acc[fm][fn][r];
      }
  }
  __syncthreads();
  if (!(wid & 1)) {
    int mbase = row0 + (wid >> 1) * 64;
#pragma unroll
    for (int fm = 0; fm < 4; fm++)
#pragma unroll
      for (int r = 0; r < 4; r++) {
        int mloc = fm * 16 + (lane >> 4) * 4 + r;
        size_t rbase = (size_t)(mbase + mloc) * I_DIM + n0h;
#pragma unroll
        for (int fn = 0; fn < 4; fn++) {
          float g = acc[fm][fn][r];
          float u = xw[mloc * 64 + fn * 16 + (lane & 15)];
          float hv = (g / (1.f + __expf(-g))) * u;
          hbuf[rbase + fn * 16 + (lane & 15)] = f2bf(hv);
        }
      }
  }
}

// ---------------- GEMM2: part[row] = h @ Wd (f16, un-gated) ----------------
__global__ __launch_bounds__(256) void gemm2_kernel(
    const unsigned short* __restrict__ hbuf, // [ROWS_CAP][I] bf16
    const unsigned short* __restrict__ wd,   // [E][H][I] bf16 (transposed)
    _Float16* __restrict__ part,             // [ROWS_CAP][H] f16
    const int* __restrict__ meta) {
  int m_t, n_t;
  remap_tile<8>(blockIdx.x, NT2 * MAX_MT, NT2, m_t, n_t);
  if (m_t >= meta[32]) return;
  int e = meta[64 + m_t];
  int row0 = meta[256 + m_t];
  int n0 = n_t * 128;

  __shared__ alignas(16) char smem[65536];

  int tid = threadIdx.x, lane = tid & 63, wid = tid >> 6;
  const unsigned short* asrc[4];
  const unsigned short* bsrc[4];
  {
    const unsigned short* wb = wd + (size_t)e * (size_t)H_DIM * I_DIM;
#pragma unroll
    for (int i = 0; i < 4; i++) {
      int r = i * 32 + (tid >> 3);
      int ch = ((tid & 7) ^ (r & 7)) * 8;
      asrc[i] = hbuf + (size_t)(row0 + r) * I_DIM + ch;
      bsrc[i] = wb + (size_t)(n0 + r) * I_DIM + ch;
    }
  }
  f32x4 acc[4][4] = {};
  int mrow = (wid >> 1) * 64 + (lane & 15);
  int brow = (wid & 1) * 64 + (lane & 15);

  constexpr int NK2 = I_DIM / BK;  // 22
  STAGE1(0, 0);
  STAGE1(1, BK);
  for (int kt = 0; kt < NK2; kt++) {
    int cur = kt & 1;
    if (kt + 1 < NK2) { asm volatile("s_waitcnt vmcnt(8)" ::: "memory"); }
    else              { asm volatile("s_waitcnt vmcnt(0)" ::: "memory"); }
    __builtin_amdgcn_s_barrier();
    const unsigned short* sA = (const unsigned short*)(smem + cur * 32768);
    const unsigned short* sB = sA + 8192;
#pragma unroll
    for (int kk = 0; kk < 2; kk++) {
      int krd = ((kk * 4 + (lane >> 4)) ^ (lane & 7)) * 8;
      short8 af[4], bf[4];
#pragma unroll
      for (int f = 0; f < 4; f++) {
        af[f] = *(const short8*)(sA + (mrow + f * 16) * BK + krd);
        bf[f] = *(const short8*)(sB + (brow + f * 16) * BK + krd);
      }
#pragma unroll
      for (int fm = 0; fm < 4; fm++)
#pragma unroll
        for (int fn = 0; fn < 4; fn++)
          acc[fm][fn] = __builtin_amdgcn_mfma_f32_16x16x32_bf16(af[fm], bf[fn], acc[fm][fn], 0, 0, 0);
    }
    asm volatile("" ::: "memory");
    __builtin_amdgcn_s_barrier();
    asm volatile("" ::: "memory");
    if (kt + 2 < NK2) STAGE1(cur, (kt + 2) * BK);
  }
  // epilogue: f16 restage into chunk-XOR-swizzled per-wave [64][64] tile,
  // then b128 coalesced stores (all waves past final barrier).
  _Float16* stg = (_Float16*)(smem + wid * 8192);
  int l15 = lane & 15;
#pragma unroll
  for (int fm = 0; fm < 4; fm++)
#pragma unroll
    for (int r = 0; r < 4; r++) {
      int mloc = fm * 16 + (lane >> 4) * 4 + r;
#pragma unroll
      for (int fn = 0; fn < 4; fn++) {
        int nl = fn * 16 + l15;
        stg[mloc * 64 + (((nl >> 3) ^ (mloc & 7)) << 3) + (nl & 7)] =
            (_Float16)acc[fm][fn][r];
      }
    }
  int m0 = (wid >> 1) * 64;
  int nbase = n0 + (wid & 1) * 64;
  int ca = lane & 7;
#pragma unroll
  for (int it = 0; it < 8; it++) {
    int mr = it * 8 + (lane >> 3);
    h16x8 v = *(const h16x8*)(stg + mr * 64 + ((ca ^ (mr & 7)) << 3));
    *(h16x8*)(part + (size_t)(row0 + m0 + mr) * H_DIM + nbase + ca * 8) = v;
  }
}

// ---------------- combine: out[t] = w0*part[r0] + w1*part[r1] --------------
__global__ __launch_bounds__(256) void combine_kernel(
    const _Float16* __restrict__ part, const int* __restrict__ tok2row,
    const float* __restrict__ topk_w, float* __restrict__ out) {
  int t = blockIdx.x;
  int c = threadIdx.x * 8;
  int r0 = tok2row[2 * t], r1 = tok2row[2 * t + 1];
  float w0 = topk_w[2 * t], w1 = topk_w[2 * t + 1];
  h16x8 p0 = *(const h16x8*)(part + (size_t)r0 * H_DIM + c);
  h16x8 p1 = *(const h16x8*)(part + (size_t)r1 * H_DIM + c);
  float* o = out + (size_t)t * H_DIM + c;
  f32x4 lo, hi;
#pragma unroll
  for (int j = 0; j < 4; j++) lo[j] = w0 * (float)p0[j] + w1 * (float)p1[j];
#pragma unroll
  for (int j = 0; j < 4; j++) hi[j] = w0 * (float)p0[4 + j] + w1 * (float)p1[4 + j];
  *(f32x4*)o = lo;
  *(f32x4*)(o + 4) = hi;
}

extern "C" void kernel_launch(void* const* d_in, const int* in_sizes, int n_in,
                              void* d_out, int out_size, void* d_ws, size_t ws_size,
                              hipStream_t stream) {
  const float* x   = (const float*)d_in[0];
  const float* rw  = (const float*)d_in[1];
  const float* wgu = (const float*)d_in[2];
  const float* wdn = (const float*)d_in[3];
  float* out = (float*)d_out;

  char* ws = (char*)d_ws;
  size_t off = 0;
  auto alloc = [&](size_t bytes) {
    void* p = ws + off;
    off += (bytes + 255) & ~(size_t)255;
    return p;
  };
  int* meta            = (int*)alloc(4096);
  int* topk_idx        = (int*)alloc((size_t)2 * T_TOK * 4);
  float* topk_w        = (float*)alloc((size_t)2 * T_TOK * 4);
  int* tok2row         = (int*)alloc((size_t)2 * T_TOK * 4);
  int* row_token       = (int*)alloc((size_t)ROWS_CAP * 4);
  unsigned short* xb    = (unsigned short*)alloc((size_t)T_TOK * H_DIM * 2);
  unsigned short* wgu_t = (unsigned short*)alloc((size_t)E_NUM * 2 * I_DIM * H_DIM * 2);
  unsigned short* wd_t  = (unsigned short*)alloc((size_t)E_NUM * H_DIM * I_DIM * 2);
  unsigned short* hbuf  = (unsigned short*)alloc((size_t)ROWS_CAP * I_DIM * 2);
  // part[ROWS_CAP][H] f16 (71.3 MB) aliases wgu_t (92.3 MB; dead after gemm1)
  _Float16* part = (_Float16*)wgu_t;

  if (off > ws_size) { // workspace too small: fail loudly (zero output)
    (void)hipMemsetAsync(d_out, 0, (size_t)out_size * sizeof(float), stream);
    return;
  }

  (void)hipMemsetAsync(meta, 0, 4096, stream);

  // weight transpose+convert (pipelined gld_lds) and routing
  tcvt2_kernel<<<TCVT_NB, 256, 0, stream>>>(wgu, wdn, wgu_t, wd_t);
  router_kernel<<<T_TOK / 4, 256, 0, stream>>>(x, rw, xb, topk_idx, topk_w, meta);
  scan_kernel<<<1, 64, 0, stream>>>(meta, row_token);
  bucket_kernel<<<(2 * T_TOK + 255) / 256, 256, 0, stream>>>(topk_idx, meta, row_token, tok2row);

  // grouped expert MLP
  gemm1_kernel<<<NT1 * MAX_MT, 256, 0, stream>>>(xb, wgu_t, hbuf, row_token, meta);
  gemm2_kernel<<<NT2 * MAX_MT, 256, 0, stream>>>(hbuf, wd_t, part, meta);
  combine_kernel<<<T_TOK, 256, 0, stream>>>(part, tok2row, topk_w, out);
}

// Round 20
// 723.964 us; speedup vs baseline: 1.0040x; 1.0040x over previous
//
#include <hip/hip_runtime.h>
#include <hip/hip_bf16.h>
#include <cstdint>
#include <cstddef>

#define T_TOK 8192
#define H_DIM 2048
#define I_DIM 1408
#define E_NUM 8
#define BM 128
#define BK 64
#define ROWS_CAP (2 * T_TOK + E_NUM * BM) /* 17408 */
#define MAX_MT (ROWS_CAP / BM)            /* 136 */
#define NT1 (I_DIM / 64)                  /* 22 */
#define NT2 (H_DIM / 128)                 /* 16 */
#define NTILE_GU (44 * 16 * E_NUM)        /* 5632 */
#define NTILE_DN (32 * 11 * E_NUM)        /* 2816 */
#define TCVT_NB 2048
#define DN_NB 512

typedef __attribute__((ext_vector_type(8))) short short8;
typedef __attribute__((ext_vector_type(4))) float f32x4;
typedef __attribute__((ext_vector_type(8))) unsigned short bf16x8;
typedef __attribute__((ext_vector_type(4))) unsigned short bf16x4;
typedef __attribute__((ext_vector_type(8))) _Float16 h16x8;

static __device__ __forceinline__ unsigned short f2bf(float f) {
  unsigned u = __float_as_uint(f);
  u += 0x7FFFu + ((u >> 16) & 1u);   // round-to-nearest-even
  return (unsigned short)(u >> 16);
}

static __device__ __forceinline__ void gld_lds16(const void* g, void* l) {
  __builtin_amdgcn_global_load_lds(
      (__attribute__((address_space(1))) unsigned int*)g,
      (__attribute__((address_space(3))) unsigned int*)l, 16, 0, 0);
}

// XCD-chunked bijective remap (nb % 8 == 0) + M-groups-of-G intra order.
template <int G>
static __device__ __forceinline__ void remap_tile(int bid, int nb, int nt_cols,
                                                  int& m_t, int& n_t) {
  int chunk = nb >> 3;
  int wg = (bid & 7) * chunk + (bid >> 3);
  int grp = wg / (nt_cols * G);
  int rem = wg % (nt_cols * G);
  n_t = rem / G;
  m_t = grp * G + rem % G;
}

// ---------------- router (fused x->bf16 convert) ---------------------------
__global__ __launch_bounds__(256) void router_kernel(
    const float* __restrict__ x, const float* __restrict__ rw,
    unsigned short* __restrict__ xb,
    int* __restrict__ topk_idx, float* __restrict__ topk_w, int* __restrict__ meta) {
  int t = blockIdx.x * 4 + (threadIdx.x >> 6);
  int lane = threadIdx.x & 63;
  const float* xr = x + (size_t)t * H_DIM;
  unsigned short* xbr = xb + (size_t)t * H_DIM;
  float acc[E_NUM];
#pragma unroll
  for (int e = 0; e < E_NUM; e++) acc[e] = 0.f;
  for (int j = lane * 4; j < H_DIM; j += 256) {
    f32x4 v = *(const f32x4*)(xr + j);
    bf16x4 b;
#pragma unroll
    for (int u = 0; u < 4; u++) b[u] = f2bf(v[u]);
    *(bf16x4*)(xbr + j) = b;
#pragma unroll
    for (int e = 0; e < E_NUM; e++) {
      f32x4 w = *(const f32x4*)(rw + e * H_DIM + j);
      acc[e] += v[0] * w[0] + v[1] * w[1] + v[2] * w[2] + v[3] * w[3];
    }
  }
#pragma unroll
  for (int e = 0; e < E_NUM; e++) {
    float v = acc[e];
#pragma unroll
    for (int s = 32; s > 0; s >>= 1) v += __shfl_xor(v, s);
    acc[e] = v;
  }
  if (lane == 0) {
    int i0 = 0;
#pragma unroll
    for (int e = 1; e < E_NUM; e++) if (acc[e] > acc[i0]) i0 = e;
    int i1 = (i0 == 0) ? 1 : 0;
#pragma unroll
    for (int e = 0; e < E_NUM; e++) if (e != i0 && acc[e] > acc[i1]) i1 = e;
    float mx = acc[0];
#pragma unroll
    for (int e = 1; e < E_NUM; e++) mx = fmaxf(mx, acc[e]);
    float sum = 0.f, p[E_NUM];
#pragma unroll
    for (int e = 0; e < E_NUM; e++) { p[e] = expf(acc[e] - mx); sum += p[e]; }
    float inv = 1.f / sum;
    topk_idx[t * 2] = i0;  topk_idx[t * 2 + 1] = i1;
    topk_w[t * 2] = p[i0] * inv;  topk_w[t * 2 + 1] = p[i1] * inv;
    atomicAdd(&meta[i0], 1);
    atomicAdd(&meta[i1], 1);
  }
}

// ---------------- scan -----------------------------------------------------
__global__ void scan_kernel(int* __restrict__ meta, int* __restrict__ row_token) {
  __shared__ int s_off[E_NUM + 1];
  if (threadIdx.x == 0) {
    int o = 0, nt = 0;
    for (int e = 0; e < E_NUM; e++) {
      meta[16 + e] = o; s_off[e] = o;
      int c = meta[e];
      int mtc = (c + BM - 1) / BM;
      for (int m = 0; m < mtc; m++) { meta[64 + nt] = e; meta[256 + nt] = o + m * BM; nt++; }
      o += mtc * BM;
      meta[8 + e] = 0; // cursor
    }
    meta[16 + E_NUM] = o; s_off[E_NUM] = o;
    meta[32] = nt;
  }
  __syncthreads();
  for (int e = 0; e < E_NUM; e++) {
    int lo = s_off[e] + meta[e], hi = s_off[e + 1];
    for (int r = lo + (int)threadIdx.x; r < hi; r += 64) row_token[r] = -1;
  }
}

// ---------------- bucket ---------------------------------------------------
__global__ __launch_bounds__(256) void bucket_kernel(
    const int* __restrict__ topk_idx, int* __restrict__ meta,
    int* __restrict__ row_token, int* __restrict__ tok2row) {
  int i = blockIdx.x * 256 + threadIdx.x;
  if (i >= 2 * T_TOK) return;
  int e = topk_idx[i];
  int pos = atomicAdd(&meta[8 + e], 1);
  int r = meta[16 + e] + pos;
  row_token[r] = i >> 1;
  tok2row[i] = r;
}

// ---------------- wgu transpose+convert (pipelined gld_lds) ----------------
// Tiles of 128 k-rows x 64 n-cols fp32 (32 KB), double-buffered; grid-stride.
__global__ __launch_bounds__(256) void tcvt_gu_kernel(
    const float* __restrict__ wgu, unsigned short* __restrict__ wgu_t) {
  __shared__ alignas(16) float st[2][128 * 64];  // 2 x 32 KB
  int tid = threadIdx.x, l = tid & 63, w = tid >> 6;
  constexpr int R = H_DIM, C = 2 * I_DIM;

  auto stage = [&](int buf, int t) {
    int e = t / 704, rem = t % 704;
    int c0 = (rem % 44) * 64, r0 = (rem / 44) * 128;
    const float* src = wgu + (size_t)e * R * C;
#pragma unroll
    for (int i = 0; i < 8; i++) {
      int rbase = w * 32 + i * 4;
      int r = rbase + (l >> 4);
      int key = (r & 7) ^ ((r >> 3) & 7);
      int c4 = ((l & 15) ^ key) * 4;  // pre-swizzled source col (f32)
      gld_lds16(src + (size_t)(r0 + r) * C + c0 + c4,
                (char*)&st[buf][0] + rbase * 256);
    }
  };
  auto process = [&](int buf, int t) {
    int e = t / 704, rem = t % 704;
    int c0 = (rem % 44) * 64, r0 = (rem / 44) * 128;
    unsigned short* dst = wgu_t + (size_t)e * R * C;
    int ca = tid & 15, cg = tid >> 4;
#pragma unroll
    for (int it = 0; it < 4; it++) {
      int c = it * 16 + cg;
      bf16x8 o;
#pragma unroll
      for (int j = 0; j < 8; j++) {
        int r = ca * 8 + j;
        int key = (r & 7) ^ ((r >> 3) & 7);
        o[j] = f2bf(st[buf][r * 64 + (((c >> 2) ^ key) << 2) + (c & 3)]);
      }
      *(bf16x8*)(dst + (size_t)(c0 + c) * R + r0 + ca * 8) = o;
    }
  };

  int t = blockIdx.x;
  if (t >= NTILE_GU) return;
  int nxt = t + TCVT_NB;
  stage(0, t);
  int buf = 0;
  while (true) {
    bool has_next = (nxt < NTILE_GU);
    if (has_next) {
      stage(buf ^ 1, nxt);
      asm volatile("s_waitcnt vmcnt(8)" ::: "memory");
    } else {
      asm volatile("s_waitcnt vmcnt(0)" ::: "memory");
    }
    __builtin_amdgcn_s_barrier();
    process(buf, t);
    if (!has_next) break;
    asm volatile("" ::: "memory");
    __builtin_amdgcn_s_barrier();
    t = nxt; nxt += TCVT_NB; buf ^= 1;
  }
}

// ---------------- GEMM1 (+ fused wdn conversion blocks) --------------------
// Blocks [0, DN_NB): wdn transpose+convert tiles (hidden under gemm1's
// compute-bound phase; gemm2 needs wd_t only after this launch completes).
// Blocks [DN_NB, ...): counted-vmcnt GEMM pipeline (unchanged).
__global__ __launch_bounds__(256) void gemm1_kernel(
    const unsigned short* __restrict__ xb,   // [T][H] bf16
    const unsigned short* __restrict__ wgu,  // [E][2I][H] bf16 (transposed)
    const float* __restrict__ wdn,           // [E][I][H] fp32 (original)
    unsigned short* __restrict__ wd_t,       // [E][H][I] bf16 out
    unsigned short* __restrict__ hbuf,       // [ROWS_CAP][I] bf16
    const int* __restrict__ row_token, const int* __restrict__ meta) {
  __shared__ alignas(16) char smem[65536];
  int tid = threadIdx.x, lane = tid & 63, wid = tid >> 6;

  if ((int)blockIdx.x < DN_NB) {
    // ---- wdn conversion path: 128x64 fp32 tiles, pipelined ----
    float* stf = (float*)smem;  // [2][128*64]
    int l = tid & 63, w = tid >> 6;
    constexpr int R = I_DIM, C = H_DIM;
    auto stage = [&](int buf, int t) {
      int e = t / 352, rem = t % 352;
      int c0 = (rem % 32) * 64, r0 = (rem / 32) * 128;
      const float* src = wdn + (size_t)e * R * C;
#pragma unroll
      for (int i = 0; i < 8; i++) {
        int rbase = w * 32 + i * 4;
        int r = rbase + (l >> 4);
        int key = (r & 7) ^ ((r >> 3) & 7);
        int c4 = ((l & 15) ^ key) * 4;
        gld_lds16(src + (size_t)(r0 + r) * C + c0 + c4,
                  (char*)stf + buf * 32768 + rbase * 256);
      }
    };
    auto process = [&](int buf, int t) {
      int e = t / 352, rem = t % 352;
      int c0 = (rem % 32) * 64, r0 = (rem / 32) * 128;
      unsigned short* dst = wd_t + (size_t)e * R * C;
      int ca = tid & 15, cg = tid >> 4;
#pragma unroll
      for (int it = 0; it < 4; it++) {
        int c = it * 16 + cg;
        bf16x8 o;
#pragma unroll
        for (int j = 0; j < 8; j++) {
          int r = ca * 8 + j;
          int key = (r & 7) ^ ((r >> 3) & 7);
          o[j] = f2bf(stf[buf * 8192 + r * 64 + (((c >> 2) ^ key) << 2) + (c & 3)]);
        }
        *(bf16x8*)(dst + (size_t)(c0 + c) * R + r0 + ca * 8) = o;
      }
    };
    int t = blockIdx.x;
    int nxt = t + DN_NB;
    stage(0, t);
    int buf = 0;
    while (true) {
      bool has_next = (nxt < NTILE_DN);
      if (has_next) {
        stage(buf ^ 1, nxt);
        asm volatile("s_waitcnt vmcnt(8)" ::: "memory");
      } else {
        asm volatile("s_waitcnt vmcnt(0)" ::: "memory");
      }
      __builtin_amdgcn_s_barrier();
      process(buf, t);
      if (!has_next) break;
      asm volatile("" ::: "memory");
      __builtin_amdgcn_s_barrier();
      t = nxt; nxt += DN_NB; buf ^= 1;
    }
    return;
  }

  // ---- GEMM path (unchanged; counted-vmcnt pipeline) ----
  int m_t, n_t;
  remap_tile<4>((int)blockIdx.x - DN_NB, NT1 * MAX_MT, NT1, m_t, n_t);
  if (m_t >= meta[32]) return;
  int e = meta[64 + m_t];
  int row0 = meta[256 + m_t];
  int n0h = n_t * 64;

  const unsigned short* asrc[4];
  const unsigned short* bsrc[4];
  {
    const unsigned short* wb = wgu + (size_t)e * (2 * (size_t)I_DIM) * H_DIM;
#pragma unroll
    for (int i = 0; i < 4; i++) {
      int r = i * 32 + (tid >> 3);
      int ch = ((tid & 7) ^ (r & 7)) * 8;  // inverse-swizzled source chunk
      int tok = row_token[row0 + r];
      if (tok < 0) tok = 0;
      asrc[i] = xb + (size_t)tok * H_DIM + ch;
      int wr = (r < 64) ? (n0h + r) : (I_DIM + n0h + (r - 64));
      bsrc[i] = wb + (size_t)wr * H_DIM + ch;
    }
  }
  f32x4 acc[4][4] = {};
  int mrow = (wid >> 1) * 64 + (lane & 15);
  int brow = (wid & 1) * 64 + (lane & 15);

#define STAGE1(buf, kof_)                                                     \
  {                                                                           \
    int kof = (kof_);                                                         \
    char* b = smem + (buf) * 32768;                                           \
    _Pragma("unroll") for (int i = 0; i < 4; i++) {                           \
      gld_lds16(asrc[i] + kof, b + i * 4096 + wid * 1024);                    \
      gld_lds16(bsrc[i] + kof, b + 16384 + i * 4096 + wid * 1024);            \
    }                                                                         \
  }

  constexpr int NK1 = H_DIM / BK;  // 32
  STAGE1(0, 0);
  STAGE1(1, BK);
  for (int kt = 0; kt < NK1; kt++) {
    int cur = kt & 1;
    if (kt + 1 < NK1) { asm volatile("s_waitcnt vmcnt(8)" ::: "memory"); }
    else              { asm volatile("s_waitcnt vmcnt(0)" ::: "memory"); }
    __builtin_amdgcn_s_barrier();
    const unsigned short* sA = (const unsigned short*)(smem + cur * 32768);
    const unsigned short* sB = sA + 8192;
#pragma unroll
    for (int kk = 0; kk < 2; kk++) {
      int krd = ((kk * 4 + (lane >> 4)) ^ (lane & 7)) * 8;
      short8 af[4], bf[4];
#pragma unroll
      for (int f = 0; f < 4; f++) {
        af[f] = *(const short8*)(sA + (mrow + f * 16) * BK + krd);
        bf[f] = *(const short8*)(sB + (brow + f * 16) * BK + krd);
      }
#pragma unroll
      for (int fm = 0; fm < 4; fm++)
#pragma unroll
        for (int fn = 0; fn < 4; fn++)
          acc[fm][fn] = __builtin_amdgcn_mfma_f32_16x16x32_bf16(af[fm], bf[fn], acc[fm][fn], 0, 0, 0);
    }
    asm volatile("" ::: "memory");
    __builtin_amdgcn_s_barrier();
    asm volatile("" ::: "memory");
    if (kt + 2 < NK1) STAGE1(cur, (kt + 2) * BK);
  }

  // SwiGLU epilogue (known-good)
  float* xw = (float*)smem + (wid >> 1) * 4096;
  if (wid & 1) {
#pragma unroll
    for (int fm = 0; fm < 4; fm++)
#pragma unroll
      for (int r = 0; r < 4; r++) {
        int mloc = fm * 16 + (lane >> 4) * 4 + r;
#pragma unroll
        for (int fn = 0; fn < 4; fn++)
          xw[mloc * 64 + fn * 16 + (lane & 15)] = acc[fm][fn][r];
      }
  }
  __syncthreads();
  if (!(wid & 1)) {
    int mbase = row0 + (wid >> 1) * 64;
#pragma unroll
    for (int fm = 0; fm < 4; fm++)
#pragma unroll
      for (int r = 0; r < 4; r++) {
        int mloc = fm * 16 + (lane >> 4) * 4 + r;
        size_t rbase = (size_t)(mbase + mloc) * I_DIM + n0h;
#pragma unroll
        for (int fn = 0; fn < 4; fn++) {
          float g = acc[fm][fn][r];
          float u = xw[mloc * 64 + fn * 16 + (lane & 15)];
          float hv = (g / (1.f + __expf(-g))) * u;
          hbuf[rbase + fn * 16 + (lane & 15)] = f2bf(hv);
        }
      }
  }
}

// ---------------- GEMM2: part[row] = h @ Wd (f16, un-gated) ----------------
__global__ __launch_bounds__(256) void gemm2_kernel(
    const unsigned short* __restrict__ hbuf, // [ROWS_CAP][I] bf16
    const unsigned short* __restrict__ wd,   // [E][H][I] bf16 (transposed)
    _Float16* __restrict__ part,             // [ROWS_CAP][H] f16
    const int* __restrict__ meta) {
  int m_t, n_t;
  remap_tile<8>(blockIdx.x, NT2 * MAX_MT, NT2, m_t, n_t);
  if (m_t >= meta[32]) return;
  int e = meta[64 + m_t];
  int row0 = meta[256 + m_t];
  int n0 = n_t * 128;

  __shared__ alignas(16) char smem[65536];

  int tid = threadIdx.x, lane = tid & 63, wid = tid >> 6;
  const unsigned short* asrc[4];
  const unsigned short* bsrc[4];
  {
    const unsigned short* wb = wd + (size_t)e * (size_t)H_DIM * I_DIM;
#pragma unroll
    for (int i = 0; i < 4; i++) {
      int r = i * 32 + (tid >> 3);
      int ch = ((tid & 7) ^ (r & 7)) * 8;
      asrc[i] = hbuf + (size_t)(row0 + r) * I_DIM + ch;
      bsrc[i] = wb + (size_t)(n0 + r) * I_DIM + ch;
    }
  }
  f32x4 acc[4][4] = {};
  int mrow = (wid >> 1) * 64 + (lane & 15);
  int brow = (wid & 1) * 64 + (lane & 15);

  constexpr int NK2 = I_DIM / BK;  // 22
  STAGE1(0, 0);
  STAGE1(1, BK);
  for (int kt = 0; kt < NK2; kt++) {
    int cur = kt & 1;
    if (kt + 1 < NK2) { asm volatile("s_waitcnt vmcnt(8)" ::: "memory"); }
    else              { asm volatile("s_waitcnt vmcnt(0)" ::: "memory"); }
    __builtin_amdgcn_s_barrier();
    const unsigned short* sA = (const unsigned short*)(smem + cur * 32768);
    const unsigned short* sB = sA + 8192;
#pragma unroll
    for (int kk = 0; kk < 2; kk++) {
      int krd = ((kk * 4 + (lane >> 4)) ^ (lane & 7)) * 8;
      short8 af[4], bf[4];
#pragma unroll
      for (int f = 0; f < 4; f++) {
        af[f] = *(const short8*)(sA + (mrow + f * 16) * BK + krd);
        bf[f] = *(const short8*)(sB + (brow + f * 16) * BK + krd);
      }
#pragma unroll
      for (int fm = 0; fm < 4; fm++)
#pragma unroll
        for (int fn = 0; fn < 4; fn++)
          acc[fm][fn] = __builtin_amdgcn_mfma_f32_16x16x32_bf16(af[fm], bf[fn], acc[fm][fn], 0, 0, 0);
    }
    asm volatile("" ::: "memory");
    __builtin_amdgcn_s_barrier();
    asm volatile("" ::: "memory");
    if (kt + 2 < NK2) STAGE1(cur, (kt + 2) * BK);
  }
  // epilogue: f16 restage into chunk-XOR-swizzled per-wave [64][64] tile,
  // then b128 coalesced stores (all waves past final barrier).
  _Float16* stg = (_Float16*)(smem + wid * 8192);
  int l15 = lane & 15;
#pragma unroll
  for (int fm = 0; fm < 4; fm++)
#pragma unroll
    for (int r = 0; r < 4; r++) {
      int mloc = fm * 16 + (lane >> 4) * 4 + r;
#pragma unroll
      for (int fn = 0; fn < 4; fn++) {
        int nl = fn * 16 + l15;
        stg[mloc * 64 + (((nl >> 3) ^ (mloc & 7)) << 3) + (nl & 7)] =
            (_Float16)acc[fm][fn][r];
      }
    }
  int m0 = (wid >> 1) * 64;
  int nbase = n0 + (wid & 1) * 64;
  int ca = lane & 7;
#pragma unroll
  for (int it = 0; it < 8; it++) {
    int mr = it * 8 + (lane >> 3);
    h16x8 v = *(const h16x8*)(stg + mr * 64 + ((ca ^ (mr & 7)) << 3));
    *(h16x8*)(part + (size_t)(row0 + m0 + mr) * H_DIM + nbase + ca * 8) = v;
  }
}

// ---------------- combine: out[t] = w0*part[r0] + w1*part[r1] --------------
__global__ __launch_bounds__(256) void combine_kernel(
    const _Float16* __restrict__ part, const int* __restrict__ tok2row,
    const float* __restrict__ topk_w, float* __restrict__ out) {
  int t = blockIdx.x;
  int c = threadIdx.x * 8;
  int r0 = tok2row[2 * t], r1 = tok2row[2 * t + 1];
  float w0 = topk_w[2 * t], w1 = topk_w[2 * t + 1];
  h16x8 p0 = *(const h16x8*)(part + (size_t)r0 * H_DIM + c);
  h16x8 p1 = *(const h16x8*)(part + (size_t)r1 * H_DIM + c);
  float* o = out + (size_t)t * H_DIM + c;
  f32x4 lo, hi;
#pragma unroll
  for (int j = 0; j < 4; j++) lo[j] = w0 * (float)p0[j] + w1 * (float)p1[j];
#pragma unroll
  for (int j = 0; j < 4; j++) hi[j] = w0 * (float)p0[4 + j] + w1 * (float)p1[4 + j];
  *(f32x4*)o = lo;
  *(f32x4*)(o + 4) = hi;
}

extern "C" void kernel_launch(void* const* d_in, const int* in_sizes, int n_in,
                              void* d_out, int out_size, void* d_ws, size_t ws_size,
                              hipStream_t stream) {
  const float* x   = (const float*)d_in[0];
  const float* rw  = (const float*)d_in[1];
  const float* wgu = (const float*)d_in[2];
  const float* wdn = (const float*)d_in[3];
  float* out = (float*)d_out;

  char* ws = (char*)d_ws;
  size_t off = 0;
  auto alloc = [&](size_t bytes) {
    void* p = ws + off;
    off += (bytes + 255) & ~(size_t)255;
    return p;
  };
  int* meta            = (int*)alloc(4096);
  int* topk_idx        = (int*)alloc((size_t)2 * T_TOK * 4);
  float* topk_w        = (float*)alloc((size_t)2 * T_TOK * 4);
  int* tok2row         = (int*)alloc((size_t)2 * T_TOK * 4);
  int* row_token       = (int*)alloc((size_t)ROWS_CAP * 4);
  unsigned short* xb    = (unsigned short*)alloc((size_t)T_TOK * H_DIM * 2);
  unsigned short* wgu_t = (unsigned short*)alloc((size_t)E_NUM * 2 * I_DIM * H_DIM * 2);
  unsigned short* wd_t  = (unsigned short*)alloc((size_t)E_NUM * H_DIM * I_DIM * 2);
  unsigned short* hbuf  = (unsigned short*)alloc((size_t)ROWS_CAP * I_DIM * 2);
  // part[ROWS_CAP][H] f16 (71.3 MB) aliases wgu_t (92.3 MB; dead after gemm1)
  _Float16* part = (_Float16*)wgu_t;

  if (off > ws_size) { // workspace too small: fail loudly (zero output)
    (void)hipMemsetAsync(d_out, 0, (size_t)out_size * sizeof(float), stream);
    return;
  }

  (void)hipMemsetAsync(meta, 0, 4096, stream);

  // wgu transpose+convert (serial; gemm1 needs it) and routing
  tcvt_gu_kernel<<<TCVT_NB, 256, 0, stream>>>(wgu, wgu_t);
  router_kernel<<<T_TOK / 4, 256, 0, stream>>>(x, rw, xb, topk_idx, topk_w, meta);
  scan_kernel<<<1, 64, 0, stream>>>(meta, row_token);
  bucket_kernel<<<(2 * T_TOK + 255) / 256, 256, 0, stream>>>(topk_idx, meta, row_token, tok2row);

  // gemm1 launch also carries the wdn conversion blocks (hidden under MFMA;
  // wd_t is complete before gemm2 by stream ordering)
  gemm1_kernel<<<DN_NB + NT1 * MAX_MT, 256, 0, stream>>>(
      xb, wgu_t, wdn, wd_t, hbuf, row_token, meta);
  gemm2_kernel<<<NT2 * MAX_MT, 256, 0, stream>>>(hbuf, wd_t, part, meta);
  combine_kernel<<<T_TOK, 256, 0, stream>>>(part, tok2row, topk_w, out);
}

// Round 21
// 702.667 us; speedup vs baseline: 1.0344x; 1.0303x over previous
//
#include <hip/hip_runtime.h>
#include <hip/hip_bf16.h>
#include <cstdint>
#include <cstddef>

#define T_TOK 8192
#define H_DIM 2048
#define I_DIM 1408
#define E_NUM 8
#define BM 128
#define BK 64
#define ROWS_CAP (2 * T_TOK + E_NUM * BM) /* 17408 */
#define MAX_MT (ROWS_CAP / BM)            /* 136 */
#define NT1 (I_DIM / 64)                  /* 22 */
#define NT2 (H_DIM / 128)                 /* 16 */
#define NTILE_GU (44 * 16 * E_NUM)        /* 5632 */
#define NTILE_DN (32 * 11 * E_NUM)        /* 2816 */
#define TCVT_NB 2048
#define DN_NB 512

typedef __attribute__((ext_vector_type(8))) short short8;
typedef __attribute__((ext_vector_type(4))) float f32x4;
typedef __attribute__((ext_vector_type(8))) unsigned short bf16x8;
typedef __attribute__((ext_vector_type(4))) unsigned short bf16x4;
typedef __attribute__((ext_vector_type(8))) _Float16 h16x8;

static __device__ __forceinline__ unsigned short f2bf(float f) {
  unsigned u = __float_as_uint(f);
  u += 0x7FFFu + ((u >> 16) & 1u);   // round-to-nearest-even
  return (unsigned short)(u >> 16);
}

static __device__ __forceinline__ void gld_lds16(const void* g, void* l) {
  __builtin_amdgcn_global_load_lds(
      (__attribute__((address_space(1))) unsigned int*)g,
      (__attribute__((address_space(3))) unsigned int*)l, 16, 0, 0);
}

// XCD-chunked bijective remap (nb % 8 == 0) + M-groups-of-G intra order.
template <int G>
static __device__ __forceinline__ void remap_tile(int bid, int nb, int nt_cols,
                                                  int& m_t, int& n_t) {
  int chunk = nb >> 3;
  int wg = (bid & 7) * chunk + (bid >> 3);
  int grp = wg / (nt_cols * G);
  int rem = wg % (nt_cols * G);
  n_t = rem / G;
  m_t = grp * G + rem % G;
}

// ---------------- prep2: wgu transpose+convert AND router, one launch ------
// Blocks [0, TCVT_NB): gu conversion, 128k x 64n fp32 tiles, double-buffered
// counted-vmcnt pipeline, grid-stride. Blocks [TCVT_NB, TCVT_NB+2048):
// router (fused x->bf16). Independent work; router rides the tail.
__global__ __launch_bounds__(256) void prep2_kernel(
    const float* __restrict__ wgu, const float* __restrict__ x,
    const float* __restrict__ rw,
    unsigned short* __restrict__ wgu_t, unsigned short* __restrict__ xb,
    int* __restrict__ topk_idx, float* __restrict__ topk_w, int* __restrict__ meta) {
  __shared__ alignas(16) float st[2][128 * 64];  // 2 x 32 KB
  int tid = threadIdx.x;
  if ((int)blockIdx.x >= TCVT_NB) {
    // ---- router path (body unchanged) ----
    int t = ((int)blockIdx.x - TCVT_NB) * 4 + (tid >> 6);
    int lane = tid & 63;
    const float* xr = x + (size_t)t * H_DIM;
    unsigned short* xbr = xb + (size_t)t * H_DIM;
    float acc[E_NUM];
#pragma unroll
    for (int e = 0; e < E_NUM; e++) acc[e] = 0.f;
    for (int j = lane * 4; j < H_DIM; j += 256) {
      f32x4 v = *(const f32x4*)(xr + j);
      bf16x4 b;
#pragma unroll
      for (int u = 0; u < 4; u++) b[u] = f2bf(v[u]);
      *(bf16x4*)(xbr + j) = b;
#pragma unroll
      for (int e = 0; e < E_NUM; e++) {
        f32x4 w = *(const f32x4*)(rw + e * H_DIM + j);
        acc[e] += v[0] * w[0] + v[1] * w[1] + v[2] * w[2] + v[3] * w[3];
      }
    }
#pragma unroll
    for (int e = 0; e < E_NUM; e++) {
      float v = acc[e];
#pragma unroll
      for (int s = 32; s > 0; s >>= 1) v += __shfl_xor(v, s);
      acc[e] = v;
    }
    if (lane == 0) {
      int i0 = 0;
#pragma unroll
      for (int e = 1; e < E_NUM; e++) if (acc[e] > acc[i0]) i0 = e;
      int i1 = (i0 == 0) ? 1 : 0;
#pragma unroll
      for (int e = 0; e < E_NUM; e++) if (e != i0 && acc[e] > acc[i1]) i1 = e;
      float mx = acc[0];
#pragma unroll
      for (int e = 1; e < E_NUM; e++) mx = fmaxf(mx, acc[e]);
      float sum = 0.f, p[E_NUM];
#pragma unroll
      for (int e = 0; e < E_NUM; e++) { p[e] = expf(acc[e] - mx); sum += p[e]; }
      float inv = 1.f / sum;
      topk_idx[t * 2] = i0;  topk_idx[t * 2 + 1] = i1;
      topk_w[t * 2] = p[i0] * inv;  topk_w[t * 2 + 1] = p[i1] * inv;
      atomicAdd(&meta[i0], 1);
      atomicAdd(&meta[i1], 1);
    }
    return;
  }
  // ---- gu conversion path (body unchanged from round-20 tcvt_gu) ----
  int l = tid & 63, w = tid >> 6;
  constexpr int R = H_DIM, C = 2 * I_DIM;
  auto stage = [&](int buf, int t) {
    int e = t / 704, rem = t % 704;
    int c0 = (rem % 44) * 64, r0 = (rem / 44) * 128;
    const float* src = wgu + (size_t)e * R * C;
#pragma unroll
    for (int i = 0; i < 8; i++) {
      int rbase = w * 32 + i * 4;
      int r = rbase + (l >> 4);
      int key = (r & 7) ^ ((r >> 3) & 7);
      int c4 = ((l & 15) ^ key) * 4;  // pre-swizzled source col (f32)
      gld_lds16(src + (size_t)(r0 + r) * C + c0 + c4,
                (char*)&st[buf][0] + rbase * 256);
    }
  };
  auto process = [&](int buf, int t) {
    int e = t / 704, rem = t % 704;
    int c0 = (rem % 44) * 64, r0 = (rem / 44) * 128;
    unsigned short* dst = wgu_t + (size_t)e * R * C;
    int ca = tid & 15, cg = tid >> 4;
#pragma unroll
    for (int it = 0; it < 4; it++) {
      int c = it * 16 + cg;
      bf16x8 o;
#pragma unroll
      for (int j = 0; j < 8; j++) {
        int r = ca * 8 + j;
        int key = (r & 7) ^ ((r >> 3) & 7);
        o[j] = f2bf(st[buf][r * 64 + (((c >> 2) ^ key) << 2) + (c & 3)]);
      }
      *(bf16x8*)(dst + (size_t)(c0 + c) * R + r0 + ca * 8) = o;
    }
  };
  int t = blockIdx.x;
  int nxt = t + TCVT_NB;
  stage(0, t);
  int buf = 0;
  while (true) {
    bool has_next = (nxt < NTILE_GU);
    if (has_next) {
      stage(buf ^ 1, nxt);
      asm volatile("s_waitcnt vmcnt(8)" ::: "memory");
    } else {
      asm volatile("s_waitcnt vmcnt(0)" ::: "memory");
    }
    __builtin_amdgcn_s_barrier();
    process(buf, t);
    if (!has_next) break;
    asm volatile("" ::: "memory");
    __builtin_amdgcn_s_barrier();
    t = nxt; nxt += TCVT_NB; buf ^= 1;
  }
}

// ---------------- scan -----------------------------------------------------
__global__ void scan_kernel(int* __restrict__ meta, int* __restrict__ row_token) {
  __shared__ int s_off[E_NUM + 1];
  if (threadIdx.x == 0) {
    int o = 0, nt = 0;
    for (int e = 0; e < E_NUM; e++) {
      meta[16 + e] = o; s_off[e] = o;
      int c = meta[e];
      int mtc = (c + BM - 1) / BM;
      for (int m = 0; m < mtc; m++) { meta[64 + nt] = e; meta[256 + nt] = o + m * BM; nt++; }
      o += mtc * BM;
      meta[8 + e] = 0; // cursor
    }
    meta[16 + E_NUM] = o; s_off[E_NUM] = o;
    meta[32] = nt;
  }
  __syncthreads();
  for (int e = 0; e < E_NUM; e++) {
    int lo = s_off[e] + meta[e], hi = s_off[e + 1];
    for (int r = lo + (int)threadIdx.x; r < hi; r += 64) row_token[r] = -1;
  }
}

// ---------------- bucket ---------------------------------------------------
__global__ __launch_bounds__(256) void bucket_kernel(
    const int* __restrict__ topk_idx, int* __restrict__ meta,
    int* __restrict__ row_token, int* __restrict__ tok2row) {
  int i = blockIdx.x * 256 + threadIdx.x;
  if (i >= 2 * T_TOK) return;
  int e = topk_idx[i];
  int pos = atomicAdd(&meta[8 + e], 1);
  int r = meta[16 + e] + pos;
  row_token[r] = i >> 1;
  tok2row[i] = r;
}

// ---------------- GEMM1 (+ fused wdn conversion blocks) --------------------
__global__ __launch_bounds__(256) void gemm1_kernel(
    const unsigned short* __restrict__ xb,   // [T][H] bf16
    const unsigned short* __restrict__ wgu,  // [E][2I][H] bf16 (transposed)
    const float* __restrict__ wdn,           // [E][I][H] fp32 (original)
    unsigned short* __restrict__ wd_t,       // [E][H][I] bf16 out
    unsigned short* __restrict__ hbuf,       // [ROWS_CAP][I] bf16
    const int* __restrict__ row_token, const int* __restrict__ meta) {
  __shared__ alignas(16) char smem[65536];
  int tid = threadIdx.x, lane = tid & 63, wid = tid >> 6;

  if ((int)blockIdx.x < DN_NB) {
    // ---- wdn conversion path: 128x64 fp32 tiles, pipelined ----
    float* stf = (float*)smem;  // [2][128*64]
    int l = tid & 63, w = tid >> 6;
    constexpr int R = I_DIM, C = H_DIM;
    auto stage = [&](int buf, int t) {
      int e = t / 352, rem = t % 352;
      int c0 = (rem % 32) * 64, r0 = (rem / 32) * 128;
      const float* src = wdn + (size_t)e * R * C;
#pragma unroll
      for (int i = 0; i < 8; i++) {
        int rbase = w * 32 + i * 4;
        int r = rbase + (l >> 4);
        int key = (r & 7) ^ ((r >> 3) & 7);
        int c4 = ((l & 15) ^ key) * 4;
        gld_lds16(src + (size_t)(r0 + r) * C + c0 + c4,
                  (char*)stf + buf * 32768 + rbase * 256);
      }
    };
    auto process = [&](int buf, int t) {
      int e = t / 352, rem = t % 352;
      int c0 = (rem % 32) * 64, r0 = (rem / 32) * 128;
      unsigned short* dst = wd_t + (size_t)e * R * C;
      int ca = tid & 15, cg = tid >> 4;
#pragma unroll
      for (int it = 0; it < 4; it++) {
        int c = it * 16 + cg;
        bf16x8 o;
#pragma unroll
        for (int j = 0; j < 8; j++) {
          int r = ca * 8 + j;
          int key = (r & 7) ^ ((r >> 3) & 7);
          o[j] = f2bf(stf[buf * 8192 + r * 64 + (((c >> 2) ^ key) << 2) + (c & 3)]);
        }
        *(bf16x8*)(dst + (size_t)(c0 + c) * R + r0 + ca * 8) = o;
      }
    };
    int t = blockIdx.x;
    int nxt = t + DN_NB;
    stage(0, t);
    int buf = 0;
    while (true) {
      bool has_next = (nxt < NTILE_DN);
      if (has_next) {
        stage(buf ^ 1, nxt);
        asm volatile("s_waitcnt vmcnt(8)" ::: "memory");
      } else {
        asm volatile("s_waitcnt vmcnt(0)" ::: "memory");
      }
      __builtin_amdgcn_s_barrier();
      process(buf, t);
      if (!has_next) break;
      asm volatile("" ::: "memory");
      __builtin_amdgcn_s_barrier();
      t = nxt; nxt += DN_NB; buf ^= 1;
    }
    return;
  }

  // ---- GEMM path (unchanged; counted-vmcnt pipeline) ----
  int m_t, n_t;
  remap_tile<4>((int)blockIdx.x - DN_NB, NT1 * MAX_MT, NT1, m_t, n_t);
  if (m_t >= meta[32]) return;
  int e = meta[64 + m_t];
  int row0 = meta[256 + m_t];
  int n0h = n_t * 64;

  const unsigned short* asrc[4];
  const unsigned short* bsrc[4];
  {
    const unsigned short* wb = wgu + (size_t)e * (2 * (size_t)I_DIM) * H_DIM;
#pragma unroll
    for (int i = 0; i < 4; i++) {
      int r = i * 32 + (tid >> 3);
      int ch = ((tid & 7) ^ (r & 7)) * 8;  // inverse-swizzled source chunk
      int tok = row_token[row0 + r];
      if (tok < 0) tok = 0;
      asrc[i] = xb + (size_t)tok * H_DIM + ch;
      int wr = (r < 64) ? (n0h + r) : (I_DIM + n0h + (r - 64));
      bsrc[i] = wb + (size_t)wr * H_DIM + ch;
    }
  }
  f32x4 acc[4][4] = {};
  int mrow = (wid >> 1) * 64 + (lane & 15);
  int brow = (wid & 1) * 64 + (lane & 15);

#define STAGE1(buf, kof_)                                                     \
  {                                                                           \
    int kof = (kof_);                                                         \
    char* b = smem + (buf) * 32768;                                           \
    _Pragma("unroll") for (int i = 0; i < 4; i++) {                           \
      gld_lds16(asrc[i] + kof, b + i * 4096 + wid * 1024);                    \
      gld_lds16(bsrc[i] + kof, b + 16384 + i * 4096 + wid * 1024);            \
    }                                                                         \
  }

  constexpr int NK1 = H_DIM / BK;  // 32
  STAGE1(0, 0);
  STAGE1(1, BK);
  for (int kt = 0; kt < NK1; kt++) {
    int cur = kt & 1;
    if (kt + 1 < NK1) { asm volatile("s_waitcnt vmcnt(8)" ::: "memory"); }
    else              { asm volatile("s_waitcnt vmcnt(0)" ::: "memory"); }
    __builtin_amdgcn_s_barrier();
    const unsigned short* sA = (const unsigned short*)(smem + cur * 32768);
    const unsigned short* sB = sA + 8192;
#pragma unroll
    for (int kk = 0; kk < 2; kk++) {
      int krd = ((kk * 4 + (lane >> 4)) ^ (lane & 7)) * 8;
      short8 af[4], bf[4];
#pragma unroll
      for (int f = 0; f < 4; f++) {
        af[f] = *(const short8*)(sA + (mrow + f * 16) * BK + krd);
        bf[f] = *(const short8*)(sB + (brow + f * 16) * BK + krd);
      }
#pragma unroll
      for (int fm = 0; fm < 4; fm++)
#pragma unroll
        for (int fn = 0; fn < 4; fn++)
          acc[fm][fn] = __builtin_amdgcn_mfma_f32_16x16x32_bf16(af[fm], bf[fn], acc[fm][fn], 0, 0, 0);
    }
    asm volatile("" ::: "memory");
    __builtin_amdgcn_s_barrier();
    asm volatile("" ::: "memory");
    if (kt + 2 < NK1) STAGE1(cur, (kt + 2) * BK);
  }

  // SwiGLU epilogue (known-good)
  float* xw = (float*)smem + (wid >> 1) * 4096;
  if (wid & 1) {
#pragma unroll
    for (int fm = 0; fm < 4; fm++)
#pragma unroll
      for (int r = 0; r < 4; r++) {
        int mloc = fm * 16 + (lane >> 4) * 4 + r;
#pragma unroll
        for (int fn = 0; fn < 4; fn++)
          xw[mloc * 64 + fn * 16 + (lane & 15)] = acc[fm][fn][r];
      }
  }
  __syncthreads();
  if (!(wid & 1)) {
    int mbase = row0 + (wid >> 1) * 64;
#pragma unroll
    for (int fm = 0; fm < 4; fm++)
#pragma unroll
      for (int r = 0; r < 4; r++) {
        int mloc = fm * 16 + (lane >> 4) * 4 + r;
        size_t rbase = (size_t)(mbase + mloc) * I_DIM + n0h;
#pragma unroll
        for (int fn = 0; fn < 4; fn++) {
          float g = acc[fm][fn][r];
          float u = xw[mloc * 64 + fn * 16 + (lane & 15)];
          float hv = (g / (1.f + __expf(-g))) * u;
          hbuf[rbase + fn * 16 + (lane & 15)] = f2bf(hv);
        }
      }
  }
}

// ---------------- GEMM2: part[row] = h @ Wd (f16, un-gated) ----------------
__global__ __launch_bounds__(256) void gemm2_kernel(
    const unsigned short* __restrict__ hbuf, // [ROWS_CAP][I] bf16
    const unsigned short* __restrict__ wd,   // [E][H][I] bf16 (transposed)
    _Float16* __restrict__ part,             // [ROWS_CAP][H] f16
    const int* __restrict__ meta) {
  int m_t, n_t;
  remap_tile<8>(blockIdx.x, NT2 * MAX_MT, NT2, m_t, n_t);
  if (m_t >= meta[32]) return;
  int e = meta[64 + m_t];
  int row0 = meta[256 + m_t];
  int n0 = n_t * 128;

  __shared__ alignas(16) char smem[65536];

  int tid = threadIdx.x, lane = tid & 63, wid = tid >> 6;
  const unsigned short* asrc[4];
  const unsigned short* bsrc[4];
  {
    const unsigned short* wb = wd + (size_t)e * (size_t)H_DIM * I_DIM;
#pragma unroll
    for (int i = 0; i < 4; i++) {
      int r = i * 32 + (tid >> 3);
      int ch = ((tid & 7) ^ (r & 7)) * 8;
      asrc[i] = hbuf + (size_t)(row0 + r) * I_DIM + ch;
      bsrc[i] = wb + (size_t)(n0 + r) * I_DIM + ch;
    }
  }
  f32x4 acc[4][4] = {};
  int mrow = (wid >> 1) * 64 + (lane & 15);
  int brow = (wid & 1) * 64 + (lane & 15);

  constexpr int NK2 = I_DIM / BK;  // 22
  STAGE1(0, 0);
  STAGE1(1, BK);
  for (int kt = 0; kt < NK2; kt++) {
    int cur = kt & 1;
    if (kt + 1 < NK2) { asm volatile("s_waitcnt vmcnt(8)" ::: "memory"); }
    else              { asm volatile("s_waitcnt vmcnt(0)" ::: "memory"); }
    __builtin_amdgcn_s_barrier();
    const unsigned short* sA = (const unsigned short*)(smem + cur * 32768);
    const unsigned short* sB = sA + 8192;
#pragma unroll
    for (int kk = 0; kk < 2; kk++) {
      int krd = ((kk * 4 + (lane >> 4)) ^ (lane & 7)) * 8;
      short8 af[4], bf[4];
#pragma unroll
      for (int f = 0; f < 4; f++) {
        af[f] = *(const short8*)(sA + (mrow + f * 16) * BK + krd);
        bf[f] = *(const short8*)(sB + (brow + f * 16) * BK + krd);
      }
#pragma unroll
      for (int fm = 0; fm < 4; fm++)
#pragma unroll
        for (int fn = 0; fn < 4; fn++)
          acc[fm][fn] = __builtin_amdgcn_mfma_f32_16x16x32_bf16(af[fm], bf[fn], acc[fm][fn], 0, 0, 0);
    }
    asm volatile("" ::: "memory");
    __builtin_amdgcn_s_barrier();
    asm volatile("" ::: "memory");
    if (kt + 2 < NK2) STAGE1(cur, (kt + 2) * BK);
  }
  // epilogue: f16 restage into chunk-XOR-swizzled per-wave [64][64] tile,
  // then b128 coalesced stores (all waves past final barrier).
  _Float16* stg = (_Float16*)(smem + wid * 8192);
  int l15 = lane & 15;
#pragma unroll
  for (int fm = 0; fm < 4; fm++)
#pragma unroll
    for (int r = 0; r < 4; r++) {
      int mloc = fm * 16 + (lane >> 4) * 4 + r;
#pragma unroll
      for (int fn = 0; fn < 4; fn++) {
        int nl = fn * 16 + l15;
        stg[mloc * 64 + (((nl >> 3) ^ (mloc & 7)) << 3) + (nl & 7)] =
            (_Float16)acc[fm][fn][r];
      }
    }
  int m0 = (wid >> 1) * 64;
  int nbase = n0 + (wid & 1) * 64;
  int ca = lane & 7;
#pragma unroll
  for (int it = 0; it < 8; it++) {
    int mr = it * 8 + (lane >> 3);
    h16x8 v = *(const h16x8*)(stg + mr * 64 + ((ca ^ (mr & 7)) << 3));
    *(h16x8*)(part + (size_t)(row0 + m0 + mr) * H_DIM + nbase + ca * 8) = v;
  }
}

// ---------------- combine: out[t] = w0*part[r0] + w1*part[r1] --------------
__global__ __launch_bounds__(256) void combine_kernel(
    const _Float16* __restrict__ part, const int* __restrict__ tok2row,
    const float* __restrict__ topk_w, float* __restrict__ out) {
  int t = blockIdx.x;
  int c = threadIdx.x * 8;
  int r0 = tok2row[2 * t], r1 = tok2row[2 * t + 1];
  float w0 = topk_w[2 * t], w1 = topk_w[2 * t + 1];
  h16x8 p0 = *(const h16x8*)(part + (size_t)r0 * H_DIM + c);
  h16x8 p1 = *(const h16x8*)(part + (size_t)r1 * H_DIM + c);
  float* o = out + (size_t)t * H_DIM + c;
  f32x4 lo, hi;
#pragma unroll
  for (int j = 0; j < 4; j++) lo[j] = w0 * (float)p0[j] + w1 * (float)p1[j];
#pragma unroll
  for (int j = 0; j < 4; j++) hi[j] = w0 * (float)p0[4 + j] + w1 * (float)p1[4 + j];
  *(f32x4*)o = lo;
  *(f32x4*)(o + 4) = hi;
}

extern "C" void kernel_launch(void* const* d_in, const int* in_sizes, int n_in,
                              void* d_out, int out_size, void* d_ws, size_t ws_size,
                              hipStream_t stream) {
  const float* x   = (const float*)d_in[0];
  const float* rw  = (const float*)d_in[1];
  const float* wgu = (const float*)d_in[2];
  const float* wdn = (const float*)d_in[3];
  float* out = (float*)d_out;

  char* ws = (char*)d_ws;
  size_t off = 0;
  auto alloc = [&](size_t bytes) {
    void* p = ws + off;
    off += (bytes + 255) & ~(size_t)255;
    return p;
  };
  int* meta            = (int*)alloc(4096);
  int* topk_idx        = (int*)alloc((size_t)2 * T_TOK * 4);
  float* topk_w        = (float*)alloc((size_t)2 * T_TOK * 4);
  int* tok2row         = (int*)alloc((size_t)2 * T_TOK * 4);
  int* row_token       = (int*)alloc((size_t)ROWS_CAP * 4);
  unsigned short* xb    = (unsigned short*)alloc((size_t)T_TOK * H_DIM * 2);
  unsigned short* wgu_t = (unsigned short*)alloc((size_t)E_NUM * 2 * I_DIM * H_DIM * 2);
  unsigned short* wd_t  = (unsigned short*)alloc((size_t)E_NUM * H_DIM * I_DIM * 2);
  unsigned short* hbuf  = (unsigned short*)alloc((size_t)ROWS_CAP * I_DIM * 2);
  // part[ROWS_CAP][H] f16 (71.3 MB) aliases wgu_t (92.3 MB; dead after gemm1)
  _Float16* part = (_Float16*)wgu_t;

  if (off > ws_size) { // workspace too small: fail loudly (zero output)
    (void)hipMemsetAsync(d_out, 0, (size_t)out_size * sizeof(float), stream);
    return;
  }

  (void)hipMemsetAsync(meta, 0, 4096, stream);

  // gu transpose+convert AND router in one launch
  prep2_kernel<<<TCVT_NB + T_TOK / 4, 256, 0, stream>>>(
      wgu, x, rw, wgu_t, xb, topk_idx, topk_w, meta);
  scan_kernel<<<1, 64, 0, stream>>>(meta, row_token);
  bucket_kernel<<<(2 * T_TOK + 255) / 256, 256, 0, stream>>>(topk_idx, meta, row_token, tok2row);

  // gemm1 launch also carries the wdn conversion blocks (hidden under MFMA;
  // wd_t is complete before gemm2 by stream ordering)
  gemm1_kernel<<<DN_NB + NT1 * MAX_MT, 256, 0, stream>>>(
      xb, wgu_t, wdn, wd_t, hbuf, row_token, meta);
  gemm2_kernel<<<NT2 * MAX_MT, 256, 0, stream>>>(hbuf, wd_t, part, meta);
  combine_kernel<<<T_TOK, 256, 0, stream>>>(part, tok2row, topk_w, out);
}

// Round 22
// 667.689 us; speedup vs baseline: 1.0886x; 1.0524x over previous
//
#include <hip/hip_runtime.h>
#include <hip/hip_bf16.h>
#include <cstdint>
#include <cstddef>

#define T_TOK 8192
#define H_DIM 2048
#define I_DIM 1408
#define E_NUM 8
#define BM 128
#define BK 64
#define ROWS_CAP (2 * T_TOK + E_NUM * BM) /* 17408 */
#define MAX_MT (ROWS_CAP / BM)            /* 136 */
#define NT1 (I_DIM / 64)                  /* 22 */
#define NT2 (H_DIM / 128)                 /* 16 */
#define NTILE_DN (32 * 11 * E_NUM)        /* 2816 (128x64 tiles) */
#define GU_NT64 (44 * 32 * E_NUM)         /* 11264 (64x64 tiles) */
#define PREP_CHAINS 2048
#define DN_NB 512

typedef __attribute__((ext_vector_type(8))) short short8;
typedef __attribute__((ext_vector_type(4))) float f32x4;
typedef __attribute__((ext_vector_type(8))) unsigned short bf16x8;
typedef __attribute__((ext_vector_type(4))) unsigned short bf16x4;
typedef __attribute__((ext_vector_type(8))) _Float16 h16x8;

static __device__ __forceinline__ unsigned short f2bf(float f) {
  unsigned u = __float_as_uint(f);
  u += 0x7FFFu + ((u >> 16) & 1u);   // round-to-nearest-even
  return (unsigned short)(u >> 16);
}

static __device__ __forceinline__ void gld_lds16(const void* g, void* l) {
  __builtin_amdgcn_global_load_lds(
      (__attribute__((address_space(1))) unsigned int*)g,
      (__attribute__((address_space(3))) unsigned int*)l, 16, 0, 0);
}

// XCD-chunked bijective remap (nb % 8 == 0) + M-groups-of-G intra order.
template <int G>
static __device__ __forceinline__ void remap_tile(int bid, int nb, int nt_cols,
                                                  int& m_t, int& n_t) {
  int chunk = nb >> 3;
  int wg = (bid & 7) * chunk + (bid >> 3);
  int grp = wg / (nt_cols * G);
  int rem = wg % (nt_cols * G);
  n_t = rem / G;
  m_t = grp * G + rem % G;
}

// ---------------- prep2: gu transpose+convert AND router, interleaved ------
// Even blockIdx: gu conversion chain (64x64 fp32 tiles, 2x16KB dbuf,
// counted-vmcnt pipeline, grid-stride). Odd blockIdx: router. 32 KB LDS
// total -> 5 blocks/CU so the router is not occupancy-throttled.
__global__ __launch_bounds__(256) void prep2_kernel(
    const float* __restrict__ wgu, const float* __restrict__ x,
    const float* __restrict__ rw,
    unsigned short* __restrict__ wgu_t, unsigned short* __restrict__ xb,
    int* __restrict__ topk_idx, float* __restrict__ topk_w, int* __restrict__ meta) {
  __shared__ alignas(16) float st[2][64 * 64];  // 2 x 16 KB
  int tid = threadIdx.x;
  if (blockIdx.x & 1) {
    // ---- router path (body unchanged) ----
    int t = ((int)blockIdx.x >> 1) * 4 + (tid >> 6);
    int lane = tid & 63;
    const float* xr = x + (size_t)t * H_DIM;
    unsigned short* xbr = xb + (size_t)t * H_DIM;
    float acc[E_NUM];
#pragma unroll
    for (int e = 0; e < E_NUM; e++) acc[e] = 0.f;
    for (int j = lane * 4; j < H_DIM; j += 256) {
      f32x4 v = *(const f32x4*)(xr + j);
      bf16x4 b;
#pragma unroll
      for (int u = 0; u < 4; u++) b[u] = f2bf(v[u]);
      *(bf16x4*)(xbr + j) = b;
#pragma unroll
      for (int e = 0; e < E_NUM; e++) {
        f32x4 w = *(const f32x4*)(rw + e * H_DIM + j);
        acc[e] += v[0] * w[0] + v[1] * w[1] + v[2] * w[2] + v[3] * w[3];
      }
    }
#pragma unroll
    for (int e = 0; e < E_NUM; e++) {
      float v = acc[e];
#pragma unroll
      for (int s = 32; s > 0; s >>= 1) v += __shfl_xor(v, s);
      acc[e] = v;
    }
    if (lane == 0) {
      int i0 = 0;
#pragma unroll
      for (int e = 1; e < E_NUM; e++) if (acc[e] > acc[i0]) i0 = e;
      int i1 = (i0 == 0) ? 1 : 0;
#pragma unroll
      for (int e = 0; e < E_NUM; e++) if (e != i0 && acc[e] > acc[i1]) i1 = e;
      float mx = acc[0];
#pragma unroll
      for (int e = 1; e < E_NUM; e++) mx = fmaxf(mx, acc[e]);
      float sum = 0.f, p[E_NUM];
#pragma unroll
      for (int e = 0; e < E_NUM; e++) { p[e] = expf(acc[e] - mx); sum += p[e]; }
      float inv = 1.f / sum;
      topk_idx[t * 2] = i0;  topk_idx[t * 2 + 1] = i1;
      topk_w[t * 2] = p[i0] * inv;  topk_w[t * 2 + 1] = p[i1] * inv;
      atomicAdd(&meta[i0], 1);
      atomicAdd(&meta[i1], 1);
    }
    return;
  }
  // ---- gu conversion path: 64x64 fp32 tiles ----
  // stage: linear LDS dest; source chunk pre-swizzled with key(r)=(r>>3)&7.
  // process: per-scalar reads 2-way banked (free); writes 128B runs/column.
  int l = tid & 63, w = tid >> 6;
  constexpr int R = H_DIM, C = 2 * I_DIM;
  auto stage = [&](int buf, int t) {
    int e = t / 1408, rem = t % 1408;   // 44 x 32 tiles per expert
    int c0 = (rem % 44) * 64, r0 = (rem / 44) * 64;
    const float* src = wgu + (size_t)e * R * C;
#pragma unroll
    for (int i = 0; i < 4; i++) {
      int rb = w * 16 + i * 4;
      int r = rb + (l >> 4);
      int ch = (l & 15) ^ ((r >> 3) & 7);
      gld_lds16(src + (size_t)(r0 + r) * C + c0 + ch * 4,
                (char*)&st[buf][0] + rb * 256);
    }
  };
  auto process = [&](int buf, int t) {
    int e = t / 1408, rem = t % 1408;
    int c0 = (rem % 44) * 64, r0 = (rem / 44) * 64;
    unsigned short* dst = wgu_t + (size_t)e * R * C;
    int a = tid & 7;
#pragma unroll
    for (int q = 0; q < 2; q++) {
      int c = (tid >> 3) + 32 * q;
      bf16x8 o;
#pragma unroll
      for (int j = 0; j < 8; j++) {
        int r = a * 8 + j;
        o[j] = f2bf(st[buf][r * 64 + (((c >> 2) ^ a) << 2) + (c & 3)]);
      }
      *(bf16x8*)(dst + (size_t)(c0 + c) * R + r0 + a * 8) = o;
    }
  };
  int t = (int)blockIdx.x >> 1;
  int nxt = t + PREP_CHAINS;
  stage(0, t);
  int buf = 0;
  while (true) {
    bool has_next = (nxt < GU_NT64);
    if (has_next) {
      stage(buf ^ 1, nxt);
      asm volatile("s_waitcnt vmcnt(4)" ::: "memory");
    } else {
      asm volatile("s_waitcnt vmcnt(0)" ::: "memory");
    }
    __builtin_amdgcn_s_barrier();
    process(buf, t);
    if (!has_next) break;
    asm volatile("" ::: "memory");
    __builtin_amdgcn_s_barrier();
    t = nxt; nxt += PREP_CHAINS; buf ^= 1;
  }
}

// ---------------- scan -----------------------------------------------------
__global__ void scan_kernel(int* __restrict__ meta, int* __restrict__ row_token) {
  __shared__ int s_off[E_NUM + 1];
  if (threadIdx.x == 0) {
    int o = 0, nt = 0;
    for (int e = 0; e < E_NUM; e++) {
      meta[16 + e] = o; s_off[e] = o;
      int c = meta[e];
      int mtc = (c + BM - 1) / BM;
      for (int m = 0; m < mtc; m++) { meta[64 + nt] = e; meta[256 + nt] = o + m * BM; nt++; }
      o += mtc * BM;
      meta[8 + e] = 0; // cursor
    }
    meta[16 + E_NUM] = o; s_off[E_NUM] = o;
    meta[32] = nt;
  }
  __syncthreads();
  for (int e = 0; e < E_NUM; e++) {
    int lo = s_off[e] + meta[e], hi = s_off[e + 1];
    for (int r = lo + (int)threadIdx.x; r < hi; r += 64) row_token[r] = -1;
  }
}

// ---------------- bucket ---------------------------------------------------
__global__ __launch_bounds__(256) void bucket_kernel(
    const int* __restrict__ topk_idx, int* __restrict__ meta,
    int* __restrict__ row_token, int* __restrict__ tok2row) {
  int i = blockIdx.x * 256 + threadIdx.x;
  if (i >= 2 * T_TOK) return;
  int e = topk_idx[i];
  int pos = atomicAdd(&meta[8 + e], 1);
  int r = meta[16 + e] + pos;
  row_token[r] = i >> 1;
  tok2row[i] = r;
}

// ---------------- GEMM1 (+ fused wdn conversion blocks) --------------------
__global__ __launch_bounds__(256) void gemm1_kernel(
    const unsigned short* __restrict__ xb,   // [T][H] bf16
    const unsigned short* __restrict__ wgu,  // [E][2I][H] bf16 (transposed)
    const float* __restrict__ wdn,           // [E][I][H] fp32 (original)
    unsigned short* __restrict__ wd_t,       // [E][H][I] bf16 out
    unsigned short* __restrict__ hbuf,       // [ROWS_CAP][I] bf16
    const int* __restrict__ row_token, const int* __restrict__ meta) {
  __shared__ alignas(16) char smem[65536];
  int tid = threadIdx.x, lane = tid & 63, wid = tid >> 6;

  if ((int)blockIdx.x < DN_NB) {
    // ---- wdn conversion path: 128x64 fp32 tiles, pipelined ----
    float* stf = (float*)smem;  // [2][128*64]
    int l = tid & 63, w = tid >> 6;
    constexpr int R = I_DIM, C = H_DIM;
    auto stage = [&](int buf, int t) {
      int e = t / 352, rem = t % 352;
      int c0 = (rem % 32) * 64, r0 = (rem / 32) * 128;
      const float* src = wdn + (size_t)e * R * C;
#pragma unroll
      for (int i = 0; i < 8; i++) {
        int rbase = w * 32 + i * 4;
        int r = rbase + (l >> 4);
        int key = (r & 7) ^ ((r >> 3) & 7);
        int c4 = ((l & 15) ^ key) * 4;
        gld_lds16(src + (size_t)(r0 + r) * C + c0 + c4,
                  (char*)stf + buf * 32768 + rbase * 256);
      }
    };
    auto process = [&](int buf, int t) {
      int e = t / 352, rem = t % 352;
      int c0 = (rem % 32) * 64, r0 = (rem / 32) * 128;
      unsigned short* dst = wd_t + (size_t)e * R * C;
      int ca = tid & 15, cg = tid >> 4;
#pragma unroll
      for (int it = 0; it < 4; it++) {
        int c = it * 16 + cg;
        bf16x8 o;
#pragma unroll
        for (int j = 0; j < 8; j++) {
          int r = ca * 8 + j;
          int key = (r & 7) ^ ((r >> 3) & 7);
          o[j] = f2bf(stf[buf * 8192 + r * 64 + (((c >> 2) ^ key) << 2) + (c & 3)]);
        }
        *(bf16x8*)(dst + (size_t)(c0 + c) * R + r0 + ca * 8) = o;
      }
    };
    int t = blockIdx.x;
    int nxt = t + DN_NB;
    stage(0, t);
    int buf = 0;
    while (true) {
      bool has_next = (nxt < NTILE_DN);
      if (has_next) {
        stage(buf ^ 1, nxt);
        asm volatile("s_waitcnt vmcnt(8)" ::: "memory");
      } else {
        asm volatile("s_waitcnt vmcnt(0)" ::: "memory");
      }
      __builtin_amdgcn_s_barrier();
      process(buf, t);
      if (!has_next) break;
      asm volatile("" ::: "memory");
      __builtin_amdgcn_s_barrier();
      t = nxt; nxt += DN_NB; buf ^= 1;
    }
    return;
  }

  // ---- GEMM path (unchanged; counted-vmcnt pipeline) ----
  int m_t, n_t;
  remap_tile<4>((int)blockIdx.x - DN_NB, NT1 * MAX_MT, NT1, m_t, n_t);
  if (m_t >= meta[32]) return;
  int e = meta[64 + m_t];
  int row0 = meta[256 + m_t];
  int n0h = n_t * 64;

  const unsigned short* asrc[4];
  const unsigned short* bsrc[4];
  {
    const unsigned short* wb = wgu + (size_t)e * (2 * (size_t)I_DIM) * H_DIM;
#pragma unroll
    for (int i = 0; i < 4; i++) {
      int r = i * 32 + (tid >> 3);
      int ch = ((tid & 7) ^ (r & 7)) * 8;  // inverse-swizzled source chunk
      int tok = row_token[row0 + r];
      if (tok < 0) tok = 0;
      asrc[i] = xb + (size_t)tok * H_DIM + ch;
      int wr = (r < 64) ? (n0h + r) : (I_DIM + n0h + (r - 64));
      bsrc[i] = wb + (size_t)wr * H_DIM + ch;
    }
  }
  f32x4 acc[4][4] = {};
  int mrow = (wid >> 1) * 64 + (lane & 15);
  int brow = (wid & 1) * 64 + (lane & 15);

#define STAGE1(buf, kof_)                                                     \
  {                                                                           \
    int kof = (kof_);                                                         \
    char* b = smem + (buf) * 32768;                                           \
    _Pragma("unroll") for (int i = 0; i < 4; i++) {                           \
      gld_lds16(asrc[i] + kof, b + i * 4096 + wid * 1024);                    \
      gld_lds16(bsrc[i] + kof, b + 16384 + i * 4096 + wid * 1024);            \
    }                                                                         \
  }

  constexpr int NK1 = H_DIM / BK;  // 32
  STAGE1(0, 0);
  STAGE1(1, BK);
  for (int kt = 0; kt < NK1; kt++) {
    int cur = kt & 1;
    if (kt + 1 < NK1) { asm volatile("s_waitcnt vmcnt(8)" ::: "memory"); }
    else              { asm volatile("s_waitcnt vmcnt(0)" ::: "memory"); }
    __builtin_amdgcn_s_barrier();
    const unsigned short* sA = (const unsigned short*)(smem + cur * 32768);
    const unsigned short* sB = sA + 8192;
#pragma unroll
    for (int kk = 0; kk < 2; kk++) {
      int krd = ((kk * 4 + (lane >> 4)) ^ (lane & 7)) * 8;
      short8 af[4], bf[4];
#pragma unroll
      for (int f = 0; f < 4; f++) {
        af[f] = *(const short8*)(sA + (mrow + f * 16) * BK + krd);
        bf[f] = *(const short8*)(sB + (brow + f * 16) * BK + krd);
      }
#pragma unroll
      for (int fm = 0; fm < 4; fm++)
#pragma unroll
        for (int fn = 0; fn < 4; fn++)
          acc[fm][fn] = __builtin_amdgcn_mfma_f32_16x16x32_bf16(af[fm], bf[fn], acc[fm][fn], 0, 0, 0);
    }
    asm volatile("" ::: "memory");
    __builtin_amdgcn_s_barrier();
    asm volatile("" ::: "memory");
    if (kt + 2 < NK1) STAGE1(cur, (kt + 2) * BK);
  }

  // SwiGLU epilogue (known-good)
  float* xw = (float*)smem + (wid >> 1) * 4096;
  if (wid & 1) {
#pragma unroll
    for (int fm = 0; fm < 4; fm++)
#pragma unroll
      for (int r = 0; r < 4; r++) {
        int mloc = fm * 16 + (lane >> 4) * 4 + r;
#pragma unroll
        for (int fn = 0; fn < 4; fn++)
          xw[mloc * 64 + fn * 16 + (lane & 15)] = acc[fm][fn][r];
      }
  }
  __syncthreads();
  if (!(wid & 1)) {
    int mbase = row0 + (wid >> 1) * 64;
#pragma unroll
    for (int fm = 0; fm < 4; fm++)
#pragma unroll
      for (int r = 0; r < 4; r++) {
        int mloc = fm * 16 + (lane >> 4) * 4 + r;
        size_t rbase = (size_t)(mbase + mloc) * I_DIM + n0h;
#pragma unroll
        for (int fn = 0; fn < 4; fn++) {
          float g = acc[fm][fn][r];
          float u = xw[mloc * 64 + fn * 16 + (lane & 15)];
          float hv = (g / (1.f + __expf(-g))) * u;
          hbuf[rbase + fn * 16 + (lane & 15)] = f2bf(hv);
        }
      }
  }
}

// ---------------- GEMM2: part[row] = h @ Wd (f16, un-gated) ----------------
__global__ __launch_bounds__(256) void gemm2_kernel(
    const unsigned short* __restrict__ hbuf, // [ROWS_CAP][I] bf16
    const unsigned short* __restrict__ wd,   // [E][H][I] bf16 (transposed)
    _Float16* __restrict__ part,             // [ROWS_CAP][H] f16
    const int* __restrict__ meta) {
  int m_t, n_t;
  remap_tile<8>(blockIdx.x, NT2 * MAX_MT, NT2, m_t, n_t);
  if (m_t >= meta[32]) return;
  int e = meta[64 + m_t];
  int row0 = meta[256 + m_t];
  int n0 = n_t * 128;

  __shared__ alignas(16) char smem[65536];

  int tid = threadIdx.x, lane = tid & 63, wid = tid >> 6;
  const unsigned short* asrc[4];
  const unsigned short* bsrc[4];
  {
    const unsigned short* wb = wd + (size_t)e * (size_t)H_DIM * I_DIM;
#pragma unroll
    for (int i = 0; i < 4; i++) {
      int r = i * 32 + (tid >> 3);
      int ch = ((tid & 7) ^ (r & 7)) * 8;
      asrc[i] = hbuf + (size_t)(row0 + r) * I_DIM + ch;
      bsrc[i] = wb + (size_t)(n0 + r) * I_DIM + ch;
    }
  }
  f32x4 acc[4][4] = {};
  int mrow = (wid >> 1) * 64 + (lane & 15);
  int brow = (wid & 1) * 64 + (lane & 15);

  constexpr int NK2 = I_DIM / BK;  // 22
  STAGE1(0, 0);
  STAGE1(1, BK);
  for (int kt = 0; kt < NK2; kt++) {
    int cur = kt & 1;
    if (kt + 1 < NK2) { asm volatile("s_waitcnt vmcnt(8)" ::: "memory"); }
    else              { asm volatile("s_waitcnt vmcnt(0)" ::: "memory"); }
    __builtin_amdgcn_s_barrier();
    const unsigned short* sA = (const unsigned short*)(smem + cur * 32768);
    const unsigned short* sB = sA + 8192;
#pragma unroll
    for (int kk = 0; kk < 2; kk++) {
      int krd = ((kk * 4 + (lane >> 4)) ^ (lane & 7)) * 8;
      short8 af[4], bf[4];
#pragma unroll
      for (int f = 0; f < 4; f++) {
        af[f] = *(const short8*)(sA + (mrow + f * 16) * BK + krd);
        bf[f] = *(const short8*)(sB + (brow + f * 16) * BK + krd);
      }
#pragma unroll
      for (int fm = 0; fm < 4; fm++)
#pragma unroll
        for (int fn = 0; fn < 4; fn++)
          acc[fm][fn] = __builtin_amdgcn_mfma_f32_16x16x32_bf16(af[fm], bf[fn], acc[fm][fn], 0, 0, 0);
    }
    asm volatile("" ::: "memory");
    __builtin_amdgcn_s_barrier();
    asm volatile("" ::: "memory");
    if (kt + 2 < NK2) STAGE1(cur, (kt + 2) * BK);
  }
  // epilogue: f16 restage into chunk-XOR-swizzled per-wave [64][64] tile,
  // then b128 coalesced stores (all waves past final barrier).
  _Float16* stg = (_Float16*)(smem + wid * 8192);
  int l15 = lane & 15;
#pragma unroll
  for (int fm = 0; fm < 4; fm++)
#pragma unroll
    for (int r = 0; r < 4; r++) {
      int mloc = fm * 16 + (lane >> 4) * 4 + r;
#pragma unroll
      for (int fn = 0; fn < 4; fn++) {
        int nl = fn * 16 + l15;
        stg[mloc * 64 + (((nl >> 3) ^ (mloc & 7)) << 3) + (nl & 7)] =
            (_Float16)acc[fm][fn][r];
      }
    }
  int m0 = (wid >> 1) * 64;
  int nbase = n0 + (wid & 1) * 64;
  int ca = lane & 7;
#pragma unroll
  for (int it = 0; it < 8; it++) {
    int mr = it * 8 + (lane >> 3);
    h16x8 v = *(const h16x8*)(stg + mr * 64 + ((ca ^ (mr & 7)) << 3));
    *(h16x8*)(part + (size_t)(row0 + m0 + mr) * H_DIM + nbase + ca * 8) = v;
  }
}

// ---------------- combine: out[t] = w0*part[r0] + w1*part[r1] --------------
__global__ __launch_bounds__(256) void combine_kernel(
    const _Float16* __restrict__ part, const int* __restrict__ tok2row,
    const float* __restrict__ topk_w, float* __restrict__ out) {
  int t = blockIdx.x;
  int c = threadIdx.x * 8;
  int r0 = tok2row[2 * t], r1 = tok2row[2 * t + 1];
  float w0 = topk_w[2 * t], w1 = topk_w[2 * t + 1];
  h16x8 p0 = *(const h16x8*)(part + (size_t)r0 * H_DIM + c);
  h16x8 p1 = *(const h16x8*)(part + (size_t)r1 * H_DIM + c);
  float* o = out + (size_t)t * H_DIM + c;
  f32x4 lo, hi;
#pragma unroll
  for (int j = 0; j < 4; j++) lo[j] = w0 * (float)p0[j] + w1 * (float)p1[j];
#pragma unroll
  for (int j = 0; j < 4; j++) hi[j] = w0 * (float)p0[4 + j] + w1 * (float)p1[4 + j];
  *(f32x4*)o = lo;
  *(f32x4*)(o + 4) = hi;
}

extern "C" void kernel_launch(void* const* d_in, const int* in_sizes, int n_in,
                              void* d_out, int out_size, void* d_ws, size_t ws_size,
                              hipStream_t stream) {
  const float* x   = (const float*)d_in[0];
  const float* rw  = (const float*)d_in[1];
  const float* wgu = (const float*)d_in[2];
  const float* wdn = (const float*)d_in[3];
  float* out = (float*)d_out;

  char* ws = (char*)d_ws;
  size_t off = 0;
  auto alloc = [&](size_t bytes) {
    void* p = ws + off;
    off += (bytes + 255) & ~(size_t)255;
    return p;
  };
  int* meta            = (int*)alloc(4096);
  int* topk_idx        = (int*)alloc((size_t)2 * T_TOK * 4);
  float* topk_w        = (float*)alloc((size_t)2 * T_TOK * 4);
  int* tok2row         = (int*)alloc((size_t)2 * T_TOK * 4);
  int* row_token       = (int*)alloc((size_t)ROWS_CAP * 4);
  unsigned short* xb    = (unsigned short*)alloc((size_t)T_TOK * H_DIM * 2);
  unsigned short* wgu_t = (unsigned short*)alloc((size_t)E_NUM * 2 * I_DIM * H_DIM * 2);
  unsigned short* wd_t  = (unsigned short*)alloc((size_t)E_NUM * H_DIM * I_DIM * 2);
  unsigned short* hbuf  = (unsigned short*)alloc((size_t)ROWS_CAP * I_DIM * 2);
  // part[ROWS_CAP][H] f16 (71.3 MB) aliases wgu_t (92.3 MB; dead after gemm1)
  _Float16* part = (_Float16*)wgu_t;

  if (off > ws_size) { // workspace too small: fail loudly (zero output)
    (void)hipMemsetAsync(d_out, 0, (size_t)out_size * sizeof(float), stream);
    return;
  }

  (void)hipMemsetAsync(meta, 0, 4096, stream);

  // gu transpose+convert AND router, parity-interleaved, one launch
  prep2_kernel<<<2 * PREP_CHAINS, 256, 0, stream>>>(
      wgu, x, rw, wgu_t, xb, topk_idx, topk_w, meta);
  scan_kernel<<<1, 64, 0, stream>>>(meta, row_token);
  bucket_kernel<<<(2 * T_TOK + 255) / 256, 256, 0, stream>>>(topk_idx, meta, row_token, tok2row);

  // gemm1 launch also carries the wdn conversion blocks (hidden under MFMA;
  // wd_t is complete before gemm2 by stream ordering)
  gemm1_kernel<<<DN_NB + NT1 * MAX_MT, 256, 0, stream>>>(
      xb, wgu_t, wdn, wd_t, hbuf, row_token, meta);
  gemm2_kernel<<<NT2 * MAX_MT, 256, 0, stream>>>(hbuf, wd_t, part, meta);
  combine_kernel<<<T_TOK, 256, 0, stream>>>(part, tok2row, topk_w, out);
}

// Round 24
// 665.755 us; speedup vs baseline: 1.0917x; 1.0029x over previous
//
#include <hip/hip_runtime.h>
#include <hip/hip_bf16.h>
#include <cstdint>
#include <cstddef>

#define T_TOK 8192
#define H_DIM 2048
#define I_DIM 1408
#define E_NUM 8
#define BM 128
#define BK 64
#define ROWS_CAP (2 * T_TOK + E_NUM * BM) /* 17408 */
#define MAX_MT (ROWS_CAP / BM)            /* 136 */
#define NT1 (I_DIM / 64)                  /* 22 */
#define NT2 (H_DIM / 128)                 /* 16 */
#define NTILE_DN (32 * 11 * E_NUM)        /* 2816 (128x64 tiles) */
#define GU_NT64 (44 * 32 * E_NUM)         /* 11264 (64x64 tiles) */
#define PREP_CHAINS 2048
#define DN_NB 512

typedef __attribute__((ext_vector_type(8))) short short8;
typedef __attribute__((ext_vector_type(4))) float f32x4;
typedef __attribute__((ext_vector_type(8))) unsigned short bf16x8;
typedef __attribute__((ext_vector_type(4))) unsigned short bf16x4;
typedef __attribute__((ext_vector_type(8))) _Float16 h16x8;

static __device__ __forceinline__ unsigned short f2bf(float f) {
  unsigned u = __float_as_uint(f);
  u += 0x7FFFu + ((u >> 16) & 1u);   // round-to-nearest-even
  return (unsigned short)(u >> 16);
}

static __device__ __forceinline__ void gld_lds16(const void* g, void* l) {
  __builtin_amdgcn_global_load_lds(
      (__attribute__((address_space(1))) unsigned int*)g,
      (__attribute__((address_space(3))) unsigned int*)l, 16, 0, 0);
}

// XCD-chunked bijective remap (nb % 8 == 0) + M-groups-of-G intra order.
template <int G>
static __device__ __forceinline__ void remap_tile(int bid, int nb, int nt_cols,
                                                  int& m_t, int& n_t) {
  int chunk = nb >> 3;
  int wg = (bid & 7) * chunk + (bid >> 3);
  int grp = wg / (nt_cols * G);
  int rem = wg % (nt_cols * G);
  n_t = rem / G;
  m_t = grp * G + rem % G;
}

// ---------------- prep2: gu transpose+convert AND router, interleaved ------
// Even blockIdx: gu conversion chain (64x64 fp32 tiles, 2x16KB dbuf,
// counted-vmcnt pipeline, grid-stride). Odd blockIdx: router. 32 KB LDS
// total -> 5 blocks/CU so the router is not occupancy-throttled.
__global__ __launch_bounds__(256) void prep2_kernel(
    const float* __restrict__ wgu, const float* __restrict__ x,
    const float* __restrict__ rw,
    unsigned short* __restrict__ wgu_t, unsigned short* __restrict__ xb,
    int* __restrict__ topk_idx, float* __restrict__ topk_w, int* __restrict__ meta) {
  __shared__ alignas(16) float st[2][64 * 64];  // 2 x 16 KB
  int tid = threadIdx.x;
  if (blockIdx.x & 1) {
    // ---- router path (body unchanged) ----
    int t = ((int)blockIdx.x >> 1) * 4 + (tid >> 6);
    int lane = tid & 63;
    const float* xr = x + (size_t)t * H_DIM;
    unsigned short* xbr = xb + (size_t)t * H_DIM;
    float acc[E_NUM];
#pragma unroll
    for (int e = 0; e < E_NUM; e++) acc[e] = 0.f;
    for (int j = lane * 4; j < H_DIM; j += 256) {
      f32x4 v = *(const f32x4*)(xr + j);
      bf16x4 b;
#pragma unroll
      for (int u = 0; u < 4; u++) b[u] = f2bf(v[u]);
      *(bf16x4*)(xbr + j) = b;
#pragma unroll
      for (int e = 0; e < E_NUM; e++) {
        f32x4 w = *(const f32x4*)(rw + e * H_DIM + j);
        acc[e] += v[0] * w[0] + v[1] * w[1] + v[2] * w[2] + v[3] * w[3];
      }
    }
#pragma unroll
    for (int e = 0; e < E_NUM; e++) {
      float v = acc[e];
#pragma unroll
      for (int s = 32; s > 0; s >>= 1) v += __shfl_xor(v, s);
      acc[e] = v;
    }
    if (lane == 0) {
      int i0 = 0;
#pragma unroll
      for (int e = 1; e < E_NUM; e++) if (acc[e] > acc[i0]) i0 = e;
      int i1 = (i0 == 0) ? 1 : 0;
#pragma unroll
      for (int e = 0; e < E_NUM; e++) if (e != i0 && acc[e] > acc[i1]) i1 = e;
      float mx = acc[0];
#pragma unroll
      for (int e = 1; e < E_NUM; e++) mx = fmaxf(mx, acc[e]);
      float sum = 0.f, p[E_NUM];
#pragma unroll
      for (int e = 0; e < E_NUM; e++) { p[e] = expf(acc[e] - mx); sum += p[e]; }
      float inv = 1.f / sum;
      topk_idx[t * 2] = i0;  topk_idx[t * 2 + 1] = i1;
      topk_w[t * 2] = p[i0] * inv;  topk_w[t * 2 + 1] = p[i1] * inv;
      atomicAdd(&meta[i0], 1);
      atomicAdd(&meta[i1], 1);
    }
    return;
  }
  // ---- gu conversion path: 64x64 fp32 tiles ----
  int l = tid & 63, w = tid >> 6;
  constexpr int R = H_DIM, C = 2 * I_DIM;
  auto stage = [&](int buf, int t) {
    int e = t / 1408, rem = t % 1408;   // 44 x 32 tiles per expert
    int c0 = (rem % 44) * 64, r0 = (rem / 44) * 64;
    const float* src = wgu + (size_t)e * R * C;
#pragma unroll
    for (int i = 0; i < 4; i++) {
      int rb = w * 16 + i * 4;
      int r = rb + (l >> 4);
      int ch = (l & 15) ^ ((r >> 3) & 7);
      gld_lds16(src + (size_t)(r0 + r) * C + c0 + ch * 4,
                (char*)&st[buf][0] + rb * 256);
    }
  };
  auto process = [&](int buf, int t) {
    int e = t / 1408, rem = t % 1408;
    int c0 = (rem % 44) * 64, r0 = (rem / 44) * 64;
    unsigned short* dst = wgu_t + (size_t)e * R * C;
    int a = tid & 7;
#pragma unroll
    for (int q = 0; q < 2; q++) {
      int c = (tid >> 3) + 32 * q;
      bf16x8 o;
#pragma unroll
      for (int j = 0; j < 8; j++) {
        int r = a * 8 + j;
        o[j] = f2bf(st[buf][r * 64 + (((c >> 2) ^ a) << 2) + (c & 3)]);
      }
      *(bf16x8*)(dst + (size_t)(c0 + c) * R + r0 + a * 8) = o;
    }
  };
  int t = (int)blockIdx.x >> 1;
  int nxt = t + PREP_CHAINS;
  stage(0, t);
  int buf = 0;
  while (true) {
    bool has_next = (nxt < GU_NT64);
    if (has_next) {
      stage(buf ^ 1, nxt);
      asm volatile("s_waitcnt vmcnt(4)" ::: "memory");
    } else {
      asm volatile("s_waitcnt vmcnt(0)" ::: "memory");
    }
    __builtin_amdgcn_s_barrier();
    process(buf, t);
    if (!has_next) break;
    asm volatile("" ::: "memory");
    __builtin_amdgcn_s_barrier();
    t = nxt; nxt += PREP_CHAINS; buf ^= 1;
  }
}

// ---------------- scan -----------------------------------------------------
__global__ void scan_kernel(int* __restrict__ meta, int* __restrict__ row_token) {
  __shared__ int s_off[E_NUM + 1];
  if (threadIdx.x == 0) {
    int o = 0, nt = 0;
    for (int e = 0; e < E_NUM; e++) {
      meta[16 + e] = o; s_off[e] = o;
      int c = meta[e];
      int mtc = (c + BM - 1) / BM;
      for (int m = 0; m < mtc; m++) { meta[64 + nt] = e; meta[256 + nt] = o + m * BM; nt++; }
      o += mtc * BM;
      meta[8 + e] = 0; // cursor
    }
    meta[16 + E_NUM] = o; s_off[E_NUM] = o;
    meta[32] = nt;
  }
  __syncthreads();
  for (int e = 0; e < E_NUM; e++) {
    int lo = s_off[e] + meta[e], hi = s_off[e + 1];
    for (int r = lo + (int)threadIdx.x; r < hi; r += 64) row_token[r] = -1;
  }
}

// ---------------- bucket ---------------------------------------------------
__global__ __launch_bounds__(256) void bucket_kernel(
    const int* __restrict__ topk_idx, int* __restrict__ meta,
    int* __restrict__ row_token, int* __restrict__ tok2row) {
  int i = blockIdx.x * 256 + threadIdx.x;
  if (i >= 2 * T_TOK) return;
  int e = topk_idx[i];
  int pos = atomicAdd(&meta[8 + e], 1);
  int r = meta[16 + e] + pos;
  row_token[r] = i >> 1;
  tok2row[i] = r;
}

// ---------------- GEMM1 (+ fused wdn conversion blocks) --------------------
__global__ __launch_bounds__(256) void gemm1_kernel(
    const unsigned short* __restrict__ xb,   // [T][H] bf16
    const unsigned short* __restrict__ wgu,  // [E][2I][H] bf16 (transposed)
    const float* __restrict__ wdn,           // [E][I][H] fp32 (original)
    unsigned short* __restrict__ wd_t,       // [E][H][I] bf16 out
    unsigned short* __restrict__ hbuf,       // [ROWS_CAP][I] bf16
    const int* __restrict__ row_token, const int* __restrict__ meta) {
  __shared__ alignas(16) char smem[65536];
  int tid = threadIdx.x, lane = tid & 63, wid = tid >> 6;

  if ((int)blockIdx.x < DN_NB) {
    // ---- wdn conversion path: 128x64 fp32 tiles, pipelined ----
    float* stf = (float*)smem;  // [2][128*64]
    int l = tid & 63, w = tid >> 6;
    constexpr int R = I_DIM, C = H_DIM;
    auto stage = [&](int buf, int t) {
      int e = t / 352, rem = t % 352;
      int c0 = (rem % 32) * 64, r0 = (rem / 32) * 128;
      const float* src = wdn + (size_t)e * R * C;
#pragma unroll
      for (int i = 0; i < 8; i++) {
        int rbase = w * 32 + i * 4;
        int r = rbase + (l >> 4);
        int key = (r & 7) ^ ((r >> 3) & 7);
        int c4 = ((l & 15) ^ key) * 4;
        gld_lds16(src + (size_t)(r0 + r) * C + c0 + c4,
                  (char*)stf + buf * 32768 + rbase * 256);
      }
    };
    auto process = [&](int buf, int t) {
      int e = t / 352, rem = t % 352;
      int c0 = (rem % 32) * 64, r0 = (rem / 32) * 128;
      unsigned short* dst = wd_t + (size_t)e * R * C;
      int ca = tid & 15, cg = tid >> 4;
#pragma unroll
      for (int it = 0; it < 4; it++) {
        int c = it * 16 + cg;
        bf16x8 o;
#pragma unroll
        for (int j = 0; j < 8; j++) {
          int r = ca * 8 + j;
          int key = (r & 7) ^ ((r >> 3) & 7);
          o[j] = f2bf(stf[buf * 8192 + r * 64 + (((c >> 2) ^ key) << 2) + (c & 3)]);
        }
        *(bf16x8*)(dst + (size_t)(c0 + c) * R + r0 + ca * 8) = o;
      }
    };
    int t = blockIdx.x;
    int nxt = t + DN_NB;
    stage(0, t);
    int buf = 0;
    while (true) {
      bool has_next = (nxt < NTILE_DN);
      if (has_next) {
        stage(buf ^ 1, nxt);
        asm volatile("s_waitcnt vmcnt(8)" ::: "memory");
      } else {
        asm volatile("s_waitcnt vmcnt(0)" ::: "memory");
      }
      __builtin_amdgcn_s_barrier();
      process(buf, t);
      if (!has_next) break;
      asm volatile("" ::: "memory");
      __builtin_amdgcn_s_barrier();
      t = nxt; nxt += DN_NB; buf ^= 1;
    }
    return;
  }

  // ---- GEMM path (unchanged; counted-vmcnt pipeline) ----
  int m_t, n_t;
  remap_tile<4>((int)blockIdx.x - DN_NB, NT1 * MAX_MT, NT1, m_t, n_t);
  if (m_t >= meta[32]) return;
  int e = meta[64 + m_t];
  int row0 = meta[256 + m_t];
  int n0h = n_t * 64;

  const unsigned short* asrc[4];
  const unsigned short* bsrc[4];
  {
    const unsigned short* wb = wgu + (size_t)e * (2 * (size_t)I_DIM) * H_DIM;
#pragma unroll
    for (int i = 0; i < 4; i++) {
      int r = i * 32 + (tid >> 3);
      int ch = ((tid & 7) ^ (r & 7)) * 8;  // inverse-swizzled source chunk
      int tok = row_token[row0 + r];
      if (tok < 0) tok = 0;
      asrc[i] = xb + (size_t)tok * H_DIM + ch;
      int wr = (r < 64) ? (n0h + r) : (I_DIM + n0h + (r - 64));
      bsrc[i] = wb + (size_t)wr * H_DIM + ch;
    }
  }
  f32x4 acc[4][4] = {};
  int mrow = (wid >> 1) * 64 + (lane & 15);
  int brow = (wid & 1) * 64 + (lane & 15);

#define STAGE1(buf, kof_)                                                     \
  {                                                                           \
    int kof = (kof_);                                                         \
    char* b = smem + (buf) * 32768;                                           \
    _Pragma("unroll") for (int i = 0; i < 4; i++) {                           \
      gld_lds16(asrc[i] + kof, b + i * 4096 + wid * 1024);                    \
      gld_lds16(bsrc[i] + kof, b + 16384 + i * 4096 + wid * 1024);            \
    }                                                                         \
  }

  constexpr int NK1 = H_DIM / BK;  // 32
  STAGE1(0, 0);
  STAGE1(1, BK);
  for (int kt = 0; kt < NK1; kt++) {
    int cur = kt & 1;
    if (kt + 1 < NK1) { asm volatile("s_waitcnt vmcnt(8)" ::: "memory"); }
    else              { asm volatile("s_waitcnt vmcnt(0)" ::: "memory"); }
    __builtin_amdgcn_s_barrier();
    const unsigned short* sA = (const unsigned short*)(smem + cur * 32768);
    const unsigned short* sB = sA + 8192;
#pragma unroll
    for (int kk = 0; kk < 2; kk++) {
      int krd = ((kk * 4 + (lane >> 4)) ^ (lane & 7)) * 8;
      short8 af[4], bf[4];
#pragma unroll
      for (int f = 0; f < 4; f++) {
        af[f] = *(const short8*)(sA + (mrow + f * 16) * BK + krd);
        bf[f] = *(const short8*)(sB + (brow + f * 16) * BK + krd);
      }
#pragma unroll
      for (int fm = 0; fm < 4; fm++)
#pragma unroll
        for (int fn = 0; fn < 4; fn++)
          acc[fm][fn] = __builtin_amdgcn_mfma_f32_16x16x32_bf16(af[fm], bf[fn], acc[fm][fn], 0, 0, 0);
    }
    asm volatile("" ::: "memory");
    __builtin_amdgcn_s_barrier();
    asm volatile("" ::: "memory");
    if (kt + 2 < NK1) STAGE1(cur, (kt + 2) * BK);
  }

  // SwiGLU epilogue (known-good)
  float* xw = (float*)smem + (wid >> 1) * 4096;
  if (wid & 1) {
#pragma unroll
    for (int fm = 0; fm < 4; fm++)
#pragma unroll
      for (int r = 0; r < 4; r++) {
        int mloc = fm * 16 + (lane >> 4) * 4 + r;
#pragma unroll
        for (int fn = 0; fn < 4; fn++)
          xw[mloc * 64 + fn * 16 + (lane & 15)] = acc[fm][fn][r];
      }
  }
  __syncthreads();
  if (!(wid & 1)) {
    int mbase = row0 + (wid >> 1) * 64;
#pragma unroll
    for (int fm = 0; fm < 4; fm++)
#pragma unroll
      for (int r = 0; r < 4; r++) {
        int mloc = fm * 16 + (lane >> 4) * 4 + r;
        size_t rbase = (size_t)(mbase + mloc) * I_DIM + n0h;
#pragma unroll
        for (int fn = 0; fn < 4; fn++) {
          float g = acc[fm][fn][r];
          float u = xw[mloc * 64 + fn * 16 + (lane & 15)];
          float hv = (g / (1.f + __expf(-g))) * u;
          hbuf[rbase + fn * 16 + (lane & 15)] = f2bf(hv);
        }
      }
  }
}

// ---------------- GEMM2: part[row] = h @ Wd (f16, un-gated) ----------------
__global__ __launch_bounds__(256) void gemm2_kernel(
    const unsigned short* __restrict__ hbuf, // [ROWS_CAP][I] bf16
    const unsigned short* __restrict__ wd,   // [E][H][I] bf16 (transposed)
    _Float16* __restrict__ part,             // [ROWS_CAP][H] f16
    const int* __restrict__ meta) {
  int m_t, n_t;
  remap_tile<8>(blockIdx.x, NT2 * MAX_MT, NT2, m_t, n_t);
  if (m_t >= meta[32]) return;
  int e = meta[64 + m_t];
  int row0 = meta[256 + m_t];
  int n0 = n_t * 128;

  __shared__ alignas(16) char smem[65536];

  int tid = threadIdx.x, lane = tid & 63, wid = tid >> 6;
  const unsigned short* asrc[4];
  const unsigned short* bsrc[4];
  {
    const unsigned short* wb = wd + (size_t)e * (size_t)H_DIM * I_DIM;
#pragma unroll
    for (int i = 0; i < 4; i++) {
      int r = i * 32 + (tid >> 3);
      int ch = ((tid & 7) ^ (r & 7)) * 8;
      asrc[i] = hbuf + (size_t)(row0 + r) * I_DIM + ch;
      bsrc[i] = wb + (size_t)(n0 + r) * I_DIM + ch;
    }
  }
  f32x4 acc[4][4] = {};
  int mrow = (wid >> 1) * 64 + (lane & 15);
  int brow = (wid & 1) * 64 + (lane & 15);

  constexpr int NK2 = I_DIM / BK;  // 22
  STAGE1(0, 0);
  STAGE1(1, BK);
  for (int kt = 0; kt < NK2; kt++) {
    int cur = kt & 1;
    if (kt + 1 < NK2) { asm volatile("s_waitcnt vmcnt(8)" ::: "memory"); }
    else              { asm volatile("s_waitcnt vmcnt(0)" ::: "memory"); }
    __builtin_amdgcn_s_barrier();
    const unsigned short* sA = (const unsigned short*)(smem + cur * 32768);
    const unsigned short* sB = sA + 8192;
#pragma unroll
    for (int kk = 0; kk < 2; kk++) {
      int krd = ((kk * 4 + (lane >> 4)) ^ (lane & 7)) * 8;
      short8 af[4], bf[4];
#pragma unroll
      for (int f = 0; f < 4; f++) {
        af[f] = *(const short8*)(sA + (mrow + f * 16) * BK + krd);
        bf[f] = *(const short8*)(sB + (brow + f * 16) * BK + krd);
      }
#pragma unroll
      for (int fm = 0; fm < 4; fm++)
#pragma unroll
        for (int fn = 0; fn < 4; fn++)
          acc[fm][fn] = __builtin_amdgcn_mfma_f32_16x16x32_bf16(af[fm], bf[fn], acc[fm][fn], 0, 0, 0);
    }
    asm volatile("" ::: "memory");
    __builtin_amdgcn_s_barrier();
    asm volatile("" ::: "memory");
    if (kt + 2 < NK2) STAGE1(cur, (kt + 2) * BK);
  }
  // epilogue: f16 restage into chunk-XOR-swizzled per-wave [64][64] tile,
  // then b128 coalesced stores (all waves past final barrier).
  _Float16* stg = (_Float16*)(smem + wid * 8192);
  int l15 = lane & 15;
#pragma unroll
  for (int fm = 0; fm < 4; fm++)
#pragma unroll
    for (int r = 0; r < 4; r++) {
      int mloc = fm * 16 + (lane >> 4) * 4 + r;
#pragma unroll
      for (int fn = 0; fn < 4; fn++) {
        int nl = fn * 16 + l15;
        stg[mloc * 64 + (((nl >> 3) ^ (mloc & 7)) << 3) + (nl & 7)] =
            (_Float16)acc[fm][fn][r];
      }
    }
  int m0 = (wid >> 1) * 64;
  int nbase = n0 + (wid & 1) * 64;
  int ca = lane & 7;
#pragma unroll
  for (int it = 0; it < 8; it++) {
    int mr = it * 8 + (lane >> 3);
    h16x8 v = *(const h16x8*)(stg + mr * 64 + ((ca ^ (mr & 7)) << 3));
    *(h16x8*)(part + (size_t)(row0 + m0 + mr) * H_DIM + nbase + ca * 8) = v;
  }
}

// ---------------- combine: out[t] = w0*part[r0] + w1*part[r1] --------------
__global__ __launch_bounds__(256) void combine_kernel(
    const _Float16* __restrict__ part, const int* __restrict__ tok2row,
    const float* __restrict__ topk_w, float* __restrict__ out) {
  int t = blockIdx.x;
  int c = threadIdx.x * 8;
  int r0 = tok2row[2 * t], r1 = tok2row[2 * t + 1];
  float w0 = topk_w[2 * t], w1 = topk_w[2 * t + 1];
  h16x8 p0 = *(const h16x8*)(part + (size_t)r0 * H_DIM + c);
  h16x8 p1 = *(const h16x8*)(part + (size_t)r1 * H_DIM + c);
  float* o = out + (size_t)t * H_DIM + c;
  f32x4 lo, hi;
#pragma unroll
  for (int j = 0; j < 4; j++) lo[j] = w0 * (float)p0[j] + w1 * (float)p1[j];
#pragma unroll
  for (int j = 0; j < 4; j++) hi[j] = w0 * (float)p0[4 + j] + w1 * (float)p1[4 + j];
  *(f32x4*)o = lo;
  *(f32x4*)(o + 4) = hi;
}

extern "C" void kernel_launch(void* const* d_in, const int* in_sizes, int n_in,
                              void* d_out, int out_size, void* d_ws, size_t ws_size,
                              hipStream_t stream) {
  const float* x   = (const float*)d_in[0];
  const float* rw  = (const float*)d_in[1];
  const float* wgu = (const float*)d_in[2];
  const float* wdn = (const float*)d_in[3];
  float* out = (float*)d_out;

  char* ws = (char*)d_ws;
  size_t off = 0;
  auto alloc = [&](size_t bytes) {
    void* p = ws + off;
    off += (bytes + 255) & ~(size_t)255;
    return p;
  };
  int* meta            = (int*)alloc(4096);
  int* topk_idx        = (int*)alloc((size_t)2 * T_TOK * 4);
  float* topk_w        = (float*)alloc((size_t)2 * T_TOK * 4);
  int* tok2row         = (int*)alloc((size_t)2 * T_TOK * 4);
  int* row_token       = (int*)alloc((size_t)ROWS_CAP * 4);
  unsigned short* xb    = (unsigned short*)alloc((size_t)T_TOK * H_DIM * 2);
  unsigned short* wgu_t = (unsigned short*)alloc((size_t)E_NUM * 2 * I_DIM * H_DIM * 2);
  unsigned short* wd_t  = (unsigned short*)alloc((size_t)E_NUM * H_DIM * I_DIM * 2);
  unsigned short* hbuf  = (unsigned short*)alloc((size_t)ROWS_CAP * I_DIM * 2);
  // part[ROWS_CAP][H] f16 (71.3 MB) aliases wgu_t (92.3 MB; dead after gemm1)
  _Float16* part = (_Float16*)wgu_t;

  if (off > ws_size) { // workspace too small: fail loudly (zero output)
    (void)hipMemsetAsync(d_out, 0, (size_t)out_size * sizeof(float), stream);
    return;
  }

  (void)hipMemsetAsync(meta, 0, 4096, stream);

  // gu transpose+convert AND router, parity-interleaved, one launch
  prep2_kernel<<<2 * PREP_CHAINS, 256, 0, stream>>>(
      wgu, x, rw, wgu_t, xb, topk_idx, topk_w, meta);
  scan_kernel<<<1, 64, 0, stream>>>(meta, row_token);
  bucket_kernel<<<(2 * T_TOK + 255) / 256, 256, 0, stream>>>(topk_idx, meta, row_token, tok2row);

  // gemm1 launch also carries the wdn conversion blocks (hidden under MFMA;
  // wd_t is complete before gemm2 by stream ordering)
  gemm1_kernel<<<DN_NB + NT1 * MAX_MT, 256, 0, stream>>>(
      xb, wgu_t, wdn, wd_t, hbuf, row_token, meta);
  gemm2_kernel<<<NT2 * MAX_MT, 256, 0, stream>>>(hbuf, wd_t, part, meta);
  combine_kernel<<<T_TOK, 256, 0, stream>>>(part, tok2row, topk_w, out);
}